// Round 4
// baseline (954.588 us; speedup 1.0000x reference)
//
#include <hip/hip_runtime.h>
#include <hip/hip_bf16.h>
#include <cstdint>

// GraphSAGE fused pipeline for MI355X.
// N=50000, E=800000, F_IN=128, HID=128, C=10.
//
// Restructuring:
//   - SAGE mean-aggregation commutes with the linear layer (segment_sum is
//     linear), so we always aggregate a 128-wide tensor.
//   - Final layer + global_mean_pool collapse to two weighted column-sums of
//     h5 plus a [128]x[128,10] matvec.
//   - Edge aggregation uses a per-call CSR build (histogram + scan + fill),
//     avoiding 512M float atomics.
//
// R1 fix: edge_index is int32 (harness: "integer -> const int*"; JAX x64 is
// disabled so jnp.int64 downcasts). R0 read it as int64 -> OOB -> abort.
// R2 hedge: clamp edge-index reads to [0,N) so a wrong dtype assumption
// yields a wrong answer (diagnosable) instead of a device fault.
// R3: byte-identical resubmit (R2 never ran: broker timeout).

#define GN 50000
#define GE 800000

__device__ __forceinline__ int clampi(int v, int n) {
  return v < 0 ? 0 : (v >= n ? n - 1 : v);
}

// ---------------- CSR build ----------------
__global__ void hist_kernel(const int* __restrict__ dst, int* __restrict__ deg, int e, int n) {
  int i = blockIdx.x * 256 + threadIdx.x;
  if (i < e) atomicAdd(&deg[clampi(dst[i], n)], 1);
}

__global__ void scan1_kernel(const int* __restrict__ deg, int* __restrict__ part,
                             int* __restrict__ bsums, int n) {
  __shared__ int s[256];
  int t = threadIdx.x;
  int i = blockIdx.x * 256 + t;
  int v = (i < n) ? deg[i] : 0;
  s[t] = v;
  __syncthreads();
  for (int o = 1; o < 256; o <<= 1) {
    int add = (t >= o) ? s[t - o] : 0;
    __syncthreads();
    s[t] += add;
    __syncthreads();
  }
  if (i < n) part[i] = s[t] - v;            // exclusive within block
  if (t == 255) bsums[blockIdx.x] = s[255]; // block total
}

__global__ void scan2_kernel(int* __restrict__ bsums, int nb) {
  __shared__ int s[256];
  int t = threadIdx.x;
  int v = (t < nb) ? bsums[t] : 0;
  s[t] = v;
  __syncthreads();
  for (int o = 1; o < 256; o <<= 1) {
    int add = (t >= o) ? s[t - o] : 0;
    __syncthreads();
    s[t] += add;
    __syncthreads();
  }
  if (t < nb) bsums[t] = s[t] - v;          // exclusive
}

__global__ void scan3_kernel(int* __restrict__ rowptr, int* __restrict__ offcur,
                             const int* __restrict__ bsums, int n, int total) {
  int i = blockIdx.x * 256 + threadIdx.x;
  if (i < n) {
    int v = rowptr[i] + bsums[blockIdx.x];
    rowptr[i] = v;
    offcur[i] = v;
  }
  if (i == 0) rowptr[n] = total;
}

__global__ void fill_kernel(const int* __restrict__ src, const int* __restrict__ dst,
                            int* __restrict__ offcur, int* __restrict__ ssrc, int e, int n) {
  int i = blockIdx.x * 256 + threadIdx.x;
  if (i < e) {
    int p = atomicAdd(&offcur[clampi(dst[i], n)], 1);
    ssrc[p] = clampi(src[i], n);
  }
}

// ws[s] = sum over edges with src==s of 1/max(deg(dst),1)  (final-layer weights)
__global__ void ws_kernel(const int* __restrict__ src, const int* __restrict__ dst,
                          const int* __restrict__ deg, float* __restrict__ wsrc, int e, int n) {
  int i = blockIdx.x * 256 + threadIdx.x;
  if (i < e) {
    int d = deg[clampi(dst[i], n)];
    atomicAdd(&wsrc[clampi(src[i], n)], 1.0f / (float)(d > 0 ? d : 1));
  }
}

// ---------------- mean aggregation (+ optional combine epilogue) ----------------
// out[i,f] = mean_{j in N(i)} feat[j,f]          (COMBINE=0)
// out[i,f] = relu(mean + radd[i,f] + bias[f])    (COMBINE=1)
template<int COMBINE>
__global__ __launch_bounds__(128) void aggregate_kernel(
    const float* __restrict__ feat, int ldf,
    const int* __restrict__ rowptr, const int* __restrict__ ssrc,
    const float* __restrict__ radd, int ldr, const float* __restrict__ bias,
    float* __restrict__ out, int ldo)
{
  __shared__ int idxs[128];
  int i = blockIdx.x;
  int f = threadIdx.x;
  int s = rowptr[i], e = rowptr[i + 1];
  float acc = 0.f;
  for (int base = s; base < e; base += 128) {
    int c = e - base; if (c > 128) c = 128;
    __syncthreads();
    if (f < c) idxs[f] = ssrc[base + f];
    __syncthreads();
    for (int t = 0; t < c; ++t)
      acc += feat[(size_t)idxs[t] * ldf + f];
  }
  int d = e - s;
  float mean = acc / (float)(d > 0 ? d : 1);
  if (COMBINE) {
    float v = mean + radd[(size_t)i * ldr + f] + bias[f];
    out[(size_t)i * ldo + f] = fmaxf(v, 0.f);
  } else {
    out[(size_t)i * ldo + f] = mean;
  }
}

// ---------------- fp32 tiled GEMM ----------------
// C[N, M] = act( [A1 | A2] @ [B1 ; B2] + bias ), K-concat at K1.
// BM=BN=64, BK=32, 256 threads, 4x4 acc per thread.
#define BM 64
#define BN 64
#define BK 32

template<int RELU>
__global__ __launch_bounds__(256) void gemm_kernel(
    const float* __restrict__ A1, const float* __restrict__ A2,
    int K1, int K, int lda1, int lda2,
    const float* __restrict__ B1, const float* __restrict__ B2,
    int ldb1, int ldb2,
    const float* __restrict__ bias,
    float* __restrict__ C, int ldc, int Nrows)
{
  __shared__ __align__(16) float As[BK][BM + 4];  // [k][m]
  __shared__ __align__(16) float Bs[BK][BN];
  int tid = threadIdx.x;
  int bm = blockIdx.x * BM;
  int bn = blockIdx.y * BN;
  int tx = tid & 15, ty = tid >> 4;
  float acc[4][4] = {};

  for (int k0 = 0; k0 < K; k0 += BK) {
    const float* Ap; int lda, kb;
    const float* Bp; int ldb;
    if (k0 < K1) { Ap = A1; lda = lda1; kb = k0;      Bp = B1 + (size_t)k0 * ldb1;        ldb = ldb1; }
    else         { Ap = A2; lda = lda2; kb = k0 - K1; Bp = B2 + (size_t)(k0 - K1) * ldb2; ldb = ldb2; }

    // load A tile (64 x 32), transpose into As[k][m]
#pragma unroll
    for (int l = 0; l < 2; ++l) {
      int li = tid + l * 256;
      int row = li >> 3;   // 0..63
      int kq  = li & 7;    // float4 slot along k
      int gr = bm + row;
      float4 a = make_float4(0.f, 0.f, 0.f, 0.f);
      if (gr < Nrows) a = *(const float4*)(Ap + (size_t)gr * lda + kb + kq * 4);
      As[kq * 4 + 0][row] = a.x;
      As[kq * 4 + 1][row] = a.y;
      As[kq * 4 + 2][row] = a.z;
      As[kq * 4 + 3][row] = a.w;
    }
    // load B tile (32 x 64) direct
#pragma unroll
    for (int l = 0; l < 2; ++l) {
      int li = tid + l * 256;
      int row = li >> 4;   // 0..31
      int cq  = li & 15;   // float4 slot along n
      float4 b = *(const float4*)(Bp + (size_t)row * ldb + bn + cq * 4);
      *(float4*)&Bs[row][cq * 4] = b;
    }
    __syncthreads();

#pragma unroll
    for (int kk = 0; kk < BK; ++kk) {
      float4 a4 = *(const float4*)&As[kk][ty * 4];
      float4 b4 = *(const float4*)&Bs[kk][tx * 4];
      float av[4] = {a4.x, a4.y, a4.z, a4.w};
      float bv[4] = {b4.x, b4.y, b4.z, b4.w};
#pragma unroll
      for (int i = 0; i < 4; ++i)
#pragma unroll
        for (int j = 0; j < 4; ++j)
          acc[i][j] = fmaf(av[i], bv[j], acc[i][j]);
    }
    __syncthreads();
  }

#pragma unroll
  for (int i = 0; i < 4; ++i) {
    int gr = bm + ty * 4 + i;
    if (gr >= Nrows) break;
#pragma unroll
    for (int j = 0; j < 4; ++j) {
      int gc = bn + tx * 4 + j;
      float v = acc[i][j];
      if (bias) v += bias[gc];
      if (RELU) v = fmaxf(v, 0.f);
      C[(size_t)gr * ldc + gc] = v;
    }
  }
}

// ---------------- final-layer reductions ----------------
// uv[0:128]  = sum_i wsrc[i] * h[i,:]
// uv[128:256]= sum_i h[i,:]
__global__ __launch_bounds__(128) void reduce_uv_kernel(const float* __restrict__ h, int ldh,
                                                        const float* __restrict__ wsrc,
                                                        float* __restrict__ uv, int n) {
  int f = threadIdx.x;
  float u = 0.f, v = 0.f;
  for (int i = blockIdx.x; i < n; i += gridDim.x) {
    float hv = h[(size_t)i * ldh + f];
    u += wsrc[i] * hv;
    v += hv;
  }
  atomicAdd(&uv[f], u);
  atomicAdd(&uv[128 + f], v);
}

__global__ void final_kernel(const float* __restrict__ uv,
                             const float* __restrict__ w4l, const float* __restrict__ w4r,
                             const float* __restrict__ b4, float* __restrict__ out) {
  __shared__ float p[10];
  int j = threadIdx.x;
  if (j < 10) {
    float s = 0.f;
    for (int k = 0; k < 128; ++k)
      s += uv[k] * w4l[k * 10 + j] + uv[128 + k] * w4r[k * 10 + j];
    float pooled = s * (1.0f / (float)GN) + b4[j];
    p[j] = pooled;
    out[j] = pooled;
  }
  __syncthreads();
  if (j == 0) {
    float m = -1e30f;
    for (int t = 0; t < 10; ++t) m = fmaxf(m, p[t]);
    float sum = 0.f;
    for (int t = 0; t < 10; ++t) sum += expf(p[t] - m);
    float lse = m + logf(sum);
    for (int t = 0; t < 10; ++t) out[10 + t] = p[t] - lse;
  }
}

extern "C" void kernel_launch(void* const* d_in, const int* in_sizes, int n_in,
                              void* d_out, int out_size, void* d_ws, size_t ws_size,
                              hipStream_t stream) {
  const float* x   = (const float*)d_in[0];
  const int*   ei  = (const int*)d_in[1];     // int32 (JAX x64 disabled)
  const float* w1l = (const float*)d_in[2];
  const float* w1r = (const float*)d_in[3];
  const float* b1  = (const float*)d_in[4];
  const float* w2l = (const float*)d_in[5];
  const float* w2r = (const float*)d_in[6];
  const float* b2  = (const float*)d_in[7];
  const float* w3l = (const float*)d_in[8];
  const float* w3r = (const float*)d_in[9];
  const float* b3  = (const float*)d_in[10];
  const float* w4l = (const float*)d_in[11];
  const float* w4r = (const float*)d_in[12];
  const float* b4  = (const float*)d_in[13];

  const int N = in_sizes[0] / 128;   // 50000
  const int E = in_sizes[1] / 2;     // 800000
  const int* src = ei;
  const int* dst = ei + E;

  // workspace carve-up (256B aligned slabs); total ~106 MB
  size_t off = 0;
  auto take = [&](size_t bytes) -> void* {
    void* p = (char*)d_ws + off;
    off += (bytes + 255) & ~(size_t)255;
    return p;
  };
  int*   deg    = (int*)take((size_t)N * 4);
  int*   rowptr = (int*)take((size_t)(N + 1) * 4);
  int*   offcur = (int*)take((size_t)N * 4);
  int*   ssrc   = (int*)take((size_t)E * 4);
  float* wsrc   = (float*)take((size_t)N * 4);
  float* h1     = (float*)take((size_t)N * 256 * 4);  // h storage (ld 256)
  float* yr     = (float*)take((size_t)N * 256 * 4);  // [y | r] per layer
  float* uv     = (float*)take(256 * 4);
  int*   bsums  = (int*)take(256 * 4);
  (void)ws_size; (void)n_in; (void)out_size;

  const int EB = (E + 255) / 256;       // 3125
  const int NB = (N + 255) / 256;       // 196
  const int GX = (N + BM - 1) / BM;     // 782

  // zero-init accumulators (ws is poisoned to 0xAA before every call)
  hipMemsetAsync(deg,  0, (size_t)N * 4, stream);
  hipMemsetAsync(wsrc, 0, (size_t)N * 4, stream);
  hipMemsetAsync(uv,   0, 256 * 4, stream);

  // ---- CSR build ----
  hist_kernel<<<EB, 256, 0, stream>>>(dst, deg, E, N);
  scan1_kernel<<<NB, 256, 0, stream>>>(deg, rowptr, bsums, N);
  scan2_kernel<<<1, 256, 0, stream>>>(bsums, NB);
  scan3_kernel<<<NB, 256, 0, stream>>>(rowptr, offcur, bsums, N, E);
  fill_kernel<<<EB, 256, 0, stream>>>(src, dst, offcur, ssrc, E, N);
  ws_kernel<<<EB, 256, 0, stream>>>(src, dst, deg, wsrc, E, N);

  // ---- layer 1: mean_x -> h1 = relu([mean_x | x] @ [w1_l ; w1_r] + b1) ----
  aggregate_kernel<0><<<N, 128, 0, stream>>>(x, 128, rowptr, ssrc,
                                             nullptr, 0, nullptr, yr, 256);
  gemm_kernel<1><<<dim3(GX, 4), 256, 0, stream>>>(yr, x, 128, 256, 256, 128,
                                                  w1l, w1r, 256, 256, b1, h1, 256, N);

  // ---- layer 2: yr = h1 @ [w2_l | w2_r]; h = relu(mean(y) + r + b2) ----
  gemm_kernel<0><<<dim3(GX, 2), 256, 0, stream>>>(h1, h1, 256, 256, 256, 256,
                                                  w2l, w2l, 128, 128, nullptr, yr, 256, N);
  gemm_kernel<0><<<dim3(GX, 2), 256, 0, stream>>>(h1, h1, 256, 256, 256, 256,
                                                  w2r, w2r, 128, 128, nullptr, yr + 128, 256, N);
  aggregate_kernel<1><<<N, 128, 0, stream>>>(yr, 256, rowptr, ssrc,
                                             yr + 128, 256, b2, h1, 256);

  // ---- layers 3-5 (shared w3) ----
  for (int rep = 0; rep < 3; ++rep) {
    gemm_kernel<0><<<dim3(GX, 2), 256, 0, stream>>>(h1, h1, 128, 128, 256, 256,
                                                    w3l, w3l, 128, 128, nullptr, yr, 256, N);
    gemm_kernel<0><<<dim3(GX, 2), 256, 0, stream>>>(h1, h1, 128, 128, 256, 256,
                                                    w3r, w3r, 128, 128, nullptr, yr + 128, 256, N);
    aggregate_kernel<1><<<N, 128, 0, stream>>>(yr, 256, rowptr, ssrc,
                                               yr + 128, 256, b3, h1, 256);
  }

  // ---- layer 6 + global mean pool, collapsed ----
  reduce_uv_kernel<<<256, 128, 0, stream>>>(h1, 256, wsrc, uv, N);
  final_kernel<<<1, 64, 0, stream>>>(uv, w4l, w4r, b4, (float*)d_out);
}

// Round 6
// 775.754 us; speedup vs baseline: 1.2305x; 1.2305x over previous
//
#include <hip/hip_runtime.h>
#include <hip/hip_bf16.h>
#include <cstdint>

// GraphSAGE fused pipeline for MI355X — R6: MFMA GEMMs (split-bf16 3-product,
// near-fp32: C = Ah.Bh + Ah.Bl + Al.Bh), single-segment A, ping-pong buffers.
//
// Activations: packed u32 = (bf16_hi << 16) | bf16_lo (4 B/elem). Weights:
// converted once/call to MFMA fragment planes, hi/lo pre-separated.
// A-tiles staged via global_load_lds(16B) with XOR chunk swizzle
// (slot ^= row&7): linear LDS dest + inverse-swizzled global source +
// swizzled ds_read (both-sides-or-neither rule).
//
// mfma_f32_16x16x32_bf16: A lane l holds A[l&15][8*(l>>4)+j]; B lane l holds
// B[8*(l>>4)+j][l&15]; C (m89-verified): col = lane&15, row = (lane>>4)*4+reg.
// Operand type is v8 __bf16 (clang sig V8y) — NOT short8.

typedef unsigned int u32;
typedef __bf16 bf16x8 __attribute__((ext_vector_type(8)));
typedef float f32x4 __attribute__((ext_vector_type(4)));

typedef __attribute__((address_space(1))) const u32 gu32;
typedef __attribute__((address_space(3))) u32 lu32;

__device__ __forceinline__ u32 bf16_hi_bits(float x) {
  u32 u = __float_as_uint(x);
  return (u + 0x7fffu + ((u >> 16) & 1u)) & 0xffff0000u;  // RNE bf16 in high 16
}
__device__ __forceinline__ u32 pack_split(float v) {
  u32 hb = bf16_hi_bits(v);
  float lo = v - __uint_as_float(hb);
  return hb | (bf16_hi_bits(lo) >> 16);
}
__device__ __forceinline__ float unpack_val(u32 p) {
  return __uint_as_float(p & 0xffff0000u) + __uint_as_float(p << 16);
}
__device__ __forceinline__ int clampi(int v, int n) {
  return v < 0 ? 0 : (v >= n ? n - 1 : v);
}

// ---------------- CSR build (unchanged from R4 green baseline) ----------------
__global__ void hist_kernel(const int* __restrict__ dst, int* __restrict__ deg, int e, int n) {
  int i = blockIdx.x * 256 + threadIdx.x;
  if (i < e) atomicAdd(&deg[clampi(dst[i], n)], 1);
}
__global__ void scan1_kernel(const int* __restrict__ deg, int* __restrict__ part,
                             int* __restrict__ bsums, int n) {
  __shared__ int s[256];
  int t = threadIdx.x;
  int i = blockIdx.x * 256 + t;
  int v = (i < n) ? deg[i] : 0;
  s[t] = v;
  __syncthreads();
  for (int o = 1; o < 256; o <<= 1) {
    int add = (t >= o) ? s[t - o] : 0;
    __syncthreads();
    s[t] += add;
    __syncthreads();
  }
  if (i < n) part[i] = s[t] - v;
  if (t == 255) bsums[blockIdx.x] = s[255];
}
__global__ void scan2_kernel(int* __restrict__ bsums, int nb) {
  __shared__ int s[256];
  int t = threadIdx.x;
  int v = (t < nb) ? bsums[t] : 0;
  s[t] = v;
  __syncthreads();
  for (int o = 1; o < 256; o <<= 1) {
    int add = (t >= o) ? s[t - o] : 0;
    __syncthreads();
    s[t] += add;
    __syncthreads();
  }
  if (t < nb) bsums[t] = s[t] - v;
}
__global__ void scan3_kernel(int* __restrict__ rowptr, int* __restrict__ offcur,
                             const int* __restrict__ bsums, int n, int total) {
  int i = blockIdx.x * 256 + threadIdx.x;
  if (i < n) {
    int v = rowptr[i] + bsums[blockIdx.x];
    rowptr[i] = v;
    offcur[i] = v;
  }
  if (i == 0) rowptr[n] = total;
}
__global__ void fill_kernel(const int* __restrict__ src, const int* __restrict__ dst,
                            int* __restrict__ offcur, int* __restrict__ ssrc, int e, int n) {
  int i = blockIdx.x * 256 + threadIdx.x;
  if (i < e) {
    int p = atomicAdd(&offcur[clampi(dst[i], n)], 1);
    ssrc[p] = clampi(src[i], n);
  }
}
__global__ void ws_kernel(const int* __restrict__ src, const int* __restrict__ dst,
                          const int* __restrict__ deg, float* __restrict__ wsrc, int e, int n) {
  int i = blockIdx.x * 256 + threadIdx.x;
  if (i < e) {
    int d = deg[clampi(dst[i], n)];
    atomicAdd(&wsrc[clampi(src[i], n)], 1.0f / (float)(d > 0 ? d : 1));
  }
}

// ---------------- conversions ----------------
// x [N,128] fp32 -> packed u32 into dst cols 128..255 of a [N,256] buffer
__global__ void xconv_kernel(const float* __restrict__ x, u32* __restrict__ dst, int n) {
  int i = blockIdx.x * 256 + threadIdx.x;
  if (i < n) dst[(size_t)(i >> 7) * 256 + 128 + (i & 127)] = pack_split(x[i]);
}

// weight [K x Msrc] fp32 row-major -> fragment plane at colbase (Mtot wide).
// frag(ks, cf): per lane 32B = 4 hi-words then 4 lo-words.
__global__ void wconv_kernel(const float* __restrict__ src, int K, int Msrc,
                             u32* __restrict__ plane, int Mtot, int colbase) {
  int t = blockIdx.x * 256 + threadIdx.x;
  int lane = t & 63, fi = t >> 6;
  int nfc = Msrc >> 4;
  if (fi >= (K >> 5) * nfc) return;
  int ks = fi / nfc, cfl = fi - ks * nfc;
  int col = cfl * 16 + (lane & 15);
  int kb = ks * 32 + (lane >> 4) * 8;
  u32 hw[4], lw[4];
#pragma unroll
  for (int jj = 0; jj < 4; ++jj) {
    u32 p0 = pack_split(src[(size_t)(kb + 2 * jj) * Msrc + col]);
    u32 p1 = pack_split(src[(size_t)(kb + 2 * jj + 1) * Msrc + col]);
    hw[jj] = (p0 >> 16) | (p1 & 0xffff0000u);
    lw[jj] = (p0 & 0xffffu) | (p1 << 16);
  }
  u32* d = plane + ((size_t)(ks * (Mtot >> 4) + (colbase >> 4) + cfl) * 64 + lane) * 8;
  *(uint4*)d = make_uint4(hw[0], hw[1], hw[2], hw[3]);
  *(uint4*)(d + 4) = make_uint4(lw[0], lw[1], lw[2], lw[3]);
}

// ---------------- MFMA GEMM ----------------
// C[N,256] = act( A @ B + bias ). A: packed u32, row stride lda, K = nk*32.
// B: fragment plane. Tile 128x128, 4 waves (2x2), wave = 64r x 64c.
#define TM 128

template<int EPI>  // 0: raw -> packed ; 1: +bias, relu -> packed
__global__ __launch_bounds__(256) void mfma_gemm(
    const u32* __restrict__ A, int lda, int nk,
    const u32* __restrict__ F,
    const float* __restrict__ bias,
    u32* __restrict__ C, int Nrows)
{
  __shared__ u32 lds[2][4096];  // 2 x 16 KB : 128 rows x 32 u32 per k-step
  const int tid = threadIdx.x;
  const int lane = tid & 63;
  const int wid = tid >> 6;
  const int bm = blockIdx.x * TM;
  const int wr0 = (wid >> 1) * 64;                      // local row base
  const int wc0 = blockIdx.y * 128 + (wid & 1) * 64;    // global col base

  f32x4 acc[4][4] = {};

  auto stage = [&](int kk, int buf) {
#pragma unroll
    for (int iss = 0; iss < 4; ++iss) {
      int s = iss * 256 + tid;          // chunk id 0..1023 (16B chunks)
      int row = s >> 3, slot = s & 7;
      int g = slot ^ (row & 7);         // inverse-swizzled global chunk
      int grow = bm + row;
      if (grow >= Nrows) grow = Nrows - 1;
      const u32* gp = A + (size_t)grow * lda + kk * 32 + g * 4;
      u32* lp = &lds[buf][(size_t)(iss * 256 + (tid & ~63)) * 4];  // wave-uniform
      __builtin_amdgcn_global_load_lds((gu32*)gp, (lu32*)lp, 16, 0, 0);
    }
  };

  stage(0, 0);
  __syncthreads();

  for (int t = 0; t < nk; ++t) {
    const int cur = t & 1;

    // B fragments (hi/lo pre-separated), L2-resident
    uint4 bh[4], bl[4];
#pragma unroll
    for (int cf = 0; cf < 4; ++cf) {
      const u32* fb = F + ((size_t)(t * 16 + (wc0 >> 4) + cf) * 64 + lane) * 8;
      bh[cf] = *(const uint4*)fb;
      bl[cf] = *(const uint4*)(fb + 4);
    }
    // prefetch next A k-tile into the other buffer
    if (t + 1 < nk) stage(t + 1, cur ^ 1);

    // A fragments from LDS (swizzled read) + hi/lo unpack
    bf16x8 ah[4], al[4];
#pragma unroll
    for (int rf = 0; rf < 4; ++rf) {
      int row = wr0 + rf * 16 + (lane & 15);
      int g0 = (lane >> 4) * 2;
      const uint4 c0 = *(const uint4*)&lds[cur][(size_t)(row * 8 + (g0 ^ (row & 7))) * 4];
      const uint4 c1 = *(const uint4*)&lds[cur][(size_t)(row * 8 + ((g0 + 1) ^ (row & 7))) * 4];
      u32 u[8] = {c0.x, c0.y, c0.z, c0.w, c1.x, c1.y, c1.z, c1.w};
      union { u32 w[4]; bf16x8 v; } H, L;
#pragma unroll
      for (int j = 0; j < 4; ++j) {
        H.w[j] = (u[2 * j] >> 16) | (u[2 * j + 1] & 0xffff0000u);
        L.w[j] = (u[2 * j] & 0xffffu) | (u[2 * j + 1] << 16);
      }
      ah[rf] = H.v;
      al[rf] = L.v;
    }
#pragma unroll
    for (int rf = 0; rf < 4; ++rf) {
#pragma unroll
      for (int cf = 0; cf < 4; ++cf) {
        union { uint4 q; bf16x8 v; } BH, BL;
        BH.q = bh[cf];
        BL.q = bl[cf];
        acc[rf][cf] = __builtin_amdgcn_mfma_f32_16x16x32_bf16(ah[rf], BH.v, acc[rf][cf], 0, 0, 0);
        acc[rf][cf] = __builtin_amdgcn_mfma_f32_16x16x32_bf16(al[rf], BH.v, acc[rf][cf], 0, 0, 0);
        acc[rf][cf] = __builtin_amdgcn_mfma_f32_16x16x32_bf16(ah[rf], BL.v, acc[rf][cf], 0, 0, 0);
      }
    }
    __syncthreads();  // drains stage + protects WAR on LDS buffers
  }

#pragma unroll
  for (int rf = 0; rf < 4; ++rf) {
    int rbase = bm + wr0 + rf * 16 + (lane >> 4) * 4;
#pragma unroll
    for (int cf = 0; cf < 4; ++cf) {
      int col = wc0 + cf * 16 + (lane & 15);
#pragma unroll
      for (int r = 0; r < 4; ++r) {
        int row = rbase + r;
        if (row < Nrows) {
          float v = acc[rf][cf][r];
          if (EPI) { v += bias[col]; v = fmaxf(v, 0.f); }
          C[(size_t)row * 256 + col] = pack_split(v);
        }
      }
    }
  }
}

// ---------------- mean aggregation (+ optional combine) ----------------
// PK=0: gather fp32 feat; PK=1: gather packed u32. Output always packed.
template<int COMBINE, int PK>
__global__ __launch_bounds__(128) void aggregate_kernel(
    const void* __restrict__ featv, int ldf,
    const int* __restrict__ rowptr, const int* __restrict__ ssrc,
    const u32* __restrict__ radd, int ldr, const float* __restrict__ bias,
    u32* __restrict__ out, int ldo)
{
  __shared__ int idxs[128];
  int i = blockIdx.x;
  int f = threadIdx.x;
  int s = rowptr[i], e = rowptr[i + 1];
  float acc = 0.f;
  for (int base = s; base < e; base += 128) {
    int c = e - base; if (c > 128) c = 128;
    __syncthreads();
    if (f < c) idxs[f] = ssrc[base + f];
    __syncthreads();
    for (int t = 0; t < c; ++t) {
      if (PK) acc += unpack_val(((const u32*)featv)[(size_t)idxs[t] * ldf + f]);
      else    acc += ((const float*)featv)[(size_t)idxs[t] * ldf + f];
    }
  }
  int d = e - s;
  float mean = acc / (float)(d > 0 ? d : 1);
  if (COMBINE) {
    float v = mean + unpack_val(radd[(size_t)i * ldr + f]) + bias[f];
    out[(size_t)i * ldo + f] = pack_split(fmaxf(v, 0.f));
  } else {
    out[(size_t)i * ldo + f] = pack_split(mean);
  }
}

// ---------------- final-layer reductions ----------------
__global__ __launch_bounds__(128) void reduce_uv_kernel(const u32* __restrict__ hp, int ldh,
                                                        const float* __restrict__ wsrc,
                                                        float* __restrict__ uv, int n) {
  int f = threadIdx.x;
  float u = 0.f, v = 0.f;
  for (int i = blockIdx.x; i < n; i += gridDim.x) {
    float hv = unpack_val(hp[(size_t)i * ldh + f]);
    u += wsrc[i] * hv;
    v += hv;
  }
  atomicAdd(&uv[f], u);
  atomicAdd(&uv[128 + f], v);
}

__global__ void final_kernel(const float* __restrict__ uv,
                             const float* __restrict__ w4l, const float* __restrict__ w4r,
                             const float* __restrict__ b4, float* __restrict__ out, int n) {
  __shared__ float p[10];
  int j = threadIdx.x;
  if (j < 10) {
    float s = 0.f;
    for (int k = 0; k < 128; ++k)
      s += uv[k] * w4l[k * 10 + j] + uv[128 + k] * w4r[k * 10 + j];
    float pooled = s * (1.0f / (float)n) + b4[j];
    p[j] = pooled;
    out[j] = pooled;
  }
  __syncthreads();
  if (j == 0) {
    float m = -1e30f;
    for (int t = 0; t < 10; ++t) m = fmaxf(m, p[t]);
    float sum = 0.f;
    for (int t = 0; t < 10; ++t) sum += expf(p[t] - m);
    float lse = m + logf(sum);
    for (int t = 0; t < 10; ++t) out[10 + t] = p[t] - lse;
  }
}

extern "C" void kernel_launch(void* const* d_in, const int* in_sizes, int n_in,
                              void* d_out, int out_size, void* d_ws, size_t ws_size,
                              hipStream_t stream) {
  const float* x   = (const float*)d_in[0];
  const int*   ei  = (const int*)d_in[1];     // int32 (JAX x64 disabled)
  const float* w1l = (const float*)d_in[2];
  const float* w1r = (const float*)d_in[3];
  const float* b1  = (const float*)d_in[4];
  const float* w2l = (const float*)d_in[5];
  const float* w2r = (const float*)d_in[6];
  const float* b2  = (const float*)d_in[7];
  const float* w3l = (const float*)d_in[8];
  const float* w3r = (const float*)d_in[9];
  const float* b3  = (const float*)d_in[10];
  const float* w4l = (const float*)d_in[11];
  const float* w4r = (const float*)d_in[12];
  const float* b4  = (const float*)d_in[13];

  const int N = in_sizes[0] / 128;   // 50000
  const int E = in_sizes[1] / 2;     // 800000
  const int* src = ei;
  const int* dst = ei + E;

  // workspace carve-up (256B aligned); total ~107 MB (R4-proven budget ~106)
  size_t off = 0;
  auto take = [&](size_t bytes) -> void* {
    void* p = (char*)d_ws + off;
    off += (bytes + 255) & ~(size_t)255;
    return p;
  };
  int*   deg    = (int*)take((size_t)N * 4);
  int*   rowptr = (int*)take((size_t)(N + 1) * 4);
  int*   offcur = (int*)take((size_t)N * 4);
  int*   ssrc   = (int*)take((size_t)E * 4);
  float* wsrc   = (float*)take((size_t)N * 4);
  int*   bsums  = (int*)take(256 * 4);
  float* uv     = (float*)take(256 * 4);
  u32*   P1     = (u32*)take(8 * 16 * 2048);   // [w1l ; w1r] K=256, M=256
  u32*   P2     = (u32*)take(8 * 16 * 2048);   // [w2l | w2r] K=256, M=256
  u32*   P3     = (u32*)take(4 * 16 * 2048);   // [w3l | w3r] K=128, M=256
  u32*   bufA   = (u32*)take((size_t)N * 256 * 4);  // [mean_x | x] -> yr ping
  u32*   bufB   = (u32*)take((size_t)N * 256 * 4);  // h1 -> h ping
  (void)ws_size; (void)n_in; (void)out_size;

  const int EB = (E + 255) / 256;
  const int NB = (N + 255) / 256;
  const int GX = (N + TM - 1) / TM;   // 391

  hipMemsetAsync(deg,  0, (size_t)N * 4, stream);
  hipMemsetAsync(wsrc, 0, (size_t)N * 4, stream);
  hipMemsetAsync(uv,   0, 256 * 4, stream);

  // ---- CSR build ----
  hist_kernel<<<EB, 256, 0, stream>>>(dst, deg, E, N);
  scan1_kernel<<<NB, 256, 0, stream>>>(deg, rowptr, bsums, N);
  scan2_kernel<<<1, 256, 0, stream>>>(bsums, NB);
  scan3_kernel<<<NB, 256, 0, stream>>>(rowptr, offcur, bsums, N, E);
  fill_kernel<<<EB, 256, 0, stream>>>(src, dst, offcur, ssrc, E, N);
  ws_kernel<<<EB, 256, 0, stream>>>(src, dst, deg, wsrc, E, N);

  // ---- conversions ----
  xconv_kernel<<<(N * 128 + 255) / 256, 256, 0, stream>>>(x, bufA, N * 128);
  wconv_kernel<<<16, 256, 0, stream>>>(w1l, 128, 256, P1, 256, 0);              // ks 0..3
  wconv_kernel<<<16, 256, 0, stream>>>(w1r, 128, 256, P1 + 4 * 16 * 512, 256, 0); // ks 4..7
  wconv_kernel<<<16, 256, 0, stream>>>(w2l, 256, 128, P2, 256, 0);
  wconv_kernel<<<16, 256, 0, stream>>>(w2r, 256, 128, P2, 256, 128);
  wconv_kernel<<<8, 256, 0, stream>>>(w3l, 128, 128, P3, 256, 0);
  wconv_kernel<<<8, 256, 0, stream>>>(w3r, 128, 128, P3, 256, 128);

  // ---- layer 1: bufA = [mean_x | x]; bufB = relu(bufA @ [w1l;w1r] + b1) ----
  aggregate_kernel<0, 0><<<N, 128, 0, stream>>>(x, 128, rowptr, ssrc,
                                                nullptr, 0, nullptr, bufA, 256);
  mfma_gemm<1><<<dim3(GX, 2), 256, 0, stream>>>(bufA, 256, 8, P1, b1, bufB, N);

  // ---- layer 2: bufA = h1 @ [w2l|w2r]; h2 -> bufB cols 0..127 ----
  mfma_gemm<0><<<dim3(GX, 2), 256, 0, stream>>>(bufB, 256, 8, P2, nullptr, bufA, N);
  aggregate_kernel<1, 1><<<N, 128, 0, stream>>>(bufA, 256, rowptr, ssrc,
                                                bufA + 128, 256, b2, bufB, 256);

  // ---- layers 3-5 (shared w3): h in bufB cols 0..127 (ld 256) ----
  for (int rep = 0; rep < 3; ++rep) {
    mfma_gemm<0><<<dim3(GX, 2), 256, 0, stream>>>(bufB, 256, 4, P3, nullptr, bufA, N);
    aggregate_kernel<1, 1><<<N, 128, 0, stream>>>(bufA, 256, rowptr, ssrc,
                                                  bufA + 128, 256, b3, bufB, 256);
  }

  // ---- layer 6 + global mean pool, collapsed ----
  reduce_uv_kernel<<<256, 128, 0, stream>>>(bufB, 256, wsrc, uv, N);
  final_kernel<<<1, 64, 0, stream>>>(uv, w4l, w4r, b4, (float*)d_out, N);
}

// Round 9
// 752.914 us; speedup vs baseline: 1.2679x; 1.0303x over previous
//
#include <hip/hip_runtime.h>
#include <hip/hip_bf16.h>
#include <cstdint>

// GraphSAGE fused pipeline for MI355X — R7 (3rd resubmit; never ran: broker).
// R6 (775 µs): MFMA split-bf16 GEMMs green; aggregates dominate (5×61 µs,
// latency-bound: 4B scalar gathers + LDS broadcast + barriers).
// R7 changes:
//  (1) aggregate v2: wave-per-node, 8B/lane uint2 gathers (full 512B row per
//      load), __shfl index broadcast (no LDS/syncthreads), 4 acc chains.
//  (2) layers 1,3-5 restructured aggregate-FIRST:
//      h' = relu([h | agg(h)] @ [w_r ; w_l] + b)  -- one K=256 GEMM, M=128,
//      bias+relu in epilogue; kills the y|r 51MB round-trip per layer.
//      Layer 2 stays gemm-first (h1 is 256-wide; agg-first would double
//      gather bytes). GEMM core machinery byte-identical to R6 (HW-verified).

typedef unsigned int u32;
typedef __bf16 bf16x8 __attribute__((ext_vector_type(8)));
typedef float f32x4 __attribute__((ext_vector_type(4)));

typedef __attribute__((address_space(1))) const u32 gu32;
typedef __attribute__((address_space(3))) u32 lu32;

__device__ __forceinline__ u32 bf16_hi_bits(float x) {
  u32 u = __float_as_uint(x);
  return (u + 0x7fffu + ((u >> 16) & 1u)) & 0xffff0000u;  // RNE bf16 in high 16
}
__device__ __forceinline__ u32 pack_split(float v) {
  u32 hb = bf16_hi_bits(v);
  float lo = v - __uint_as_float(hb);
  return hb | (bf16_hi_bits(lo) >> 16);
}
__device__ __forceinline__ float unpack_val(u32 p) {
  return __uint_as_float(p & 0xffff0000u) + __uint_as_float(p << 16);
}
__device__ __forceinline__ int clampi(int v, int n) {
  return v < 0 ? 0 : (v >= n ? n - 1 : v);
}

// ---------------- CSR build (unchanged, HW-verified) ----------------
__global__ void hist_kernel(const int* __restrict__ dst, int* __restrict__ deg, int e, int n) {
  int i = blockIdx.x * 256 + threadIdx.x;
  if (i < e) atomicAdd(&deg[clampi(dst[i], n)], 1);
}
__global__ void scan1_kernel(const int* __restrict__ deg, int* __restrict__ part,
                             int* __restrict__ bsums, int n) {
  __shared__ int s[256];
  int t = threadIdx.x;
  int i = blockIdx.x * 256 + t;
  int v = (i < n) ? deg[i] : 0;
  s[t] = v;
  __syncthreads();
  for (int o = 1; o < 256; o <<= 1) {
    int add = (t >= o) ? s[t - o] : 0;
    __syncthreads();
    s[t] += add;
    __syncthreads();
  }
  if (i < n) part[i] = s[t] - v;
  if (t == 255) bsums[blockIdx.x] = s[255];
}
__global__ void scan2_kernel(int* __restrict__ bsums, int nb) {
  __shared__ int s[256];
  int t = threadIdx.x;
  int v = (t < nb) ? bsums[t] : 0;
  s[t] = v;
  __syncthreads();
  for (int o = 1; o < 256; o <<= 1) {
    int add = (t >= o) ? s[t - o] : 0;
    __syncthreads();
    s[t] += add;
    __syncthreads();
  }
  if (t < nb) bsums[t] = s[t] - v;
}
__global__ void scan3_kernel(int* __restrict__ rowptr, int* __restrict__ offcur,
                             const int* __restrict__ bsums, int n, int total) {
  int i = blockIdx.x * 256 + threadIdx.x;
  if (i < n) {
    int v = rowptr[i] + bsums[blockIdx.x];
    rowptr[i] = v;
    offcur[i] = v;
  }
  if (i == 0) rowptr[n] = total;
}
__global__ void fill_kernel(const int* __restrict__ src, const int* __restrict__ dst,
                            int* __restrict__ offcur, int* __restrict__ ssrc, int e, int n) {
  int i = blockIdx.x * 256 + threadIdx.x;
  if (i < e) {
    int p = atomicAdd(&offcur[clampi(dst[i], n)], 1);
    ssrc[p] = clampi(src[i], n);
  }
}
__global__ void ws_kernel(const int* __restrict__ src, const int* __restrict__ dst,
                          const int* __restrict__ deg, float* __restrict__ wsrc, int e, int n) {
  int i = blockIdx.x * 256 + threadIdx.x;
  if (i < e) {
    int d = deg[clampi(dst[i], n)];
    atomicAdd(&wsrc[clampi(src[i], n)], 1.0f / (float)(d > 0 ? d : 1));
  }
}

// ---------------- conversions ----------------
// x [N,128] fp32 -> packed u32 into cols 128..255 of a [N,256] buffer
__global__ void xconv_kernel(const float* __restrict__ x, u32* __restrict__ dst, int n) {
  int i = blockIdx.x * 256 + threadIdx.x;
  if (i < n) dst[(size_t)(i >> 7) * 256 + 128 + (i & 127)] = pack_split(x[i]);
}

// weight [K x Msrc] fp32 row-major -> fragment plane at colbase (Mtot wide).
// frag(ks, cf): per lane 32B = 4 hi-words then 4 lo-words.
__global__ void wconv_kernel(const float* __restrict__ src, int K, int Msrc,
                             u32* __restrict__ plane, int Mtot, int colbase) {
  int t = blockIdx.x * 256 + threadIdx.x;
  int lane = t & 63, fi = t >> 6;
  int nfc = Msrc >> 4;
  if (fi >= (K >> 5) * nfc) return;
  int ks = fi / nfc, cfl = fi - ks * nfc;
  int col = cfl * 16 + (lane & 15);
  int kb = ks * 32 + (lane >> 4) * 8;
  u32 hw[4], lw[4];
#pragma unroll
  for (int jj = 0; jj < 4; ++jj) {
    u32 p0 = pack_split(src[(size_t)(kb + 2 * jj) * Msrc + col]);
    u32 p1 = pack_split(src[(size_t)(kb + 2 * jj + 1) * Msrc + col]);
    hw[jj] = (p0 >> 16) | (p1 & 0xffff0000u);
    lw[jj] = (p0 & 0xffffu) | (p1 << 16);
  }
  u32* d = plane + ((size_t)(ks * (Mtot >> 4) + (colbase >> 4) + cfl) * 64 + lane) * 8;
  *(uint4*)d = make_uint4(hw[0], hw[1], hw[2], hw[3]);
  *(uint4*)(d + 4) = make_uint4(lw[0], lw[1], lw[2], lw[3]);
}

// ---------------- MFMA GEMM (core identical to R6; mcols param added) -------
// C[.,M] = act( A @ B + bias ). A packed u32 [Nrows, 256] (K = nk*32).
// B fragment plane, mcols = M>>4. Tile 128x128, 4 waves (2x2).
#define TM 128

template<int EPI>  // 0: raw -> packed ; 1: +bias, relu -> packed
__global__ __launch_bounds__(256) void mfma_gemm(
    const u32* __restrict__ A, int lda, int nk,
    const u32* __restrict__ F, int mcols,
    const float* __restrict__ bias,
    u32* __restrict__ C, int ldc, int Nrows)
{
  __shared__ u32 lds[2][4096];  // 2 x 16 KB : 128 rows x 32 u32 per k-step
  const int tid = threadIdx.x;
  const int lane = tid & 63;
  const int wid = tid >> 6;
  const int bm = blockIdx.x * TM;
  const int wr0 = (wid >> 1) * 64;                      // local row base
  const int wc0 = blockIdx.y * 128 + (wid & 1) * 64;    // global col base

  f32x4 acc[4][4] = {};

  auto stage = [&](int kk, int buf) {
#pragma unroll
    for (int iss = 0; iss < 4; ++iss) {
      int s = iss * 256 + tid;          // chunk id 0..1023 (16B chunks)
      int row = s >> 3, slot = s & 7;
      int g = slot ^ (row & 7);         // inverse-swizzled global chunk
      int grow = bm + row;
      if (grow >= Nrows) grow = Nrows - 1;
      const u32* gp = A + (size_t)grow * lda + kk * 32 + g * 4;
      u32* lp = &lds[buf][(size_t)(iss * 256 + (tid & ~63)) * 4];  // wave-uniform
      __builtin_amdgcn_global_load_lds((gu32*)gp, (lu32*)lp, 16, 0, 0);
    }
  };

  stage(0, 0);
  __syncthreads();

  for (int t = 0; t < nk; ++t) {
    const int cur = t & 1;

    // B fragments (hi/lo pre-separated), L2-resident
    uint4 bh[4], bl[4];
#pragma unroll
    for (int cf = 0; cf < 4; ++cf) {
      const u32* fb = F + ((size_t)(t * mcols + (wc0 >> 4) + cf) * 64 + lane) * 8;
      bh[cf] = *(const uint4*)fb;
      bl[cf] = *(const uint4*)(fb + 4);
    }
    // prefetch next A k-tile into the other buffer
    if (t + 1 < nk) stage(t + 1, cur ^ 1);

    // A fragments from LDS (swizzled read) + hi/lo unpack
    bf16x8 ah[4], al[4];
#pragma unroll
    for (int rf = 0; rf < 4; ++rf) {
      int row = wr0 + rf * 16 + (lane & 15);
      int g0 = (lane >> 4) * 2;
      const uint4 c0 = *(const uint4*)&lds[cur][(size_t)(row * 8 + (g0 ^ (row & 7))) * 4];
      const uint4 c1 = *(const uint4*)&lds[cur][(size_t)(row * 8 + ((g0 + 1) ^ (row & 7))) * 4];
      u32 u[8] = {c0.x, c0.y, c0.z, c0.w, c1.x, c1.y, c1.z, c1.w};
      union { u32 w[4]; bf16x8 v; } H, L;
#pragma unroll
      for (int j = 0; j < 4; ++j) {
        H.w[j] = (u[2 * j] >> 16) | (u[2 * j + 1] & 0xffff0000u);
        L.w[j] = (u[2 * j] & 0xffffu) | (u[2 * j + 1] << 16);
      }
      ah[rf] = H.v;
      al[rf] = L.v;
    }
#pragma unroll
    for (int rf = 0; rf < 4; ++rf) {
#pragma unroll
      for (int cf = 0; cf < 4; ++cf) {
        union { uint4 q; bf16x8 v; } BH, BL;
        BH.q = bh[cf];
        BL.q = bl[cf];
        acc[rf][cf] = __builtin_amdgcn_mfma_f32_16x16x32_bf16(ah[rf], BH.v, acc[rf][cf], 0, 0, 0);
        acc[rf][cf] = __builtin_amdgcn_mfma_f32_16x16x32_bf16(al[rf], BH.v, acc[rf][cf], 0, 0, 0);
        acc[rf][cf] = __builtin_amdgcn_mfma_f32_16x16x32_bf16(ah[rf], BL.v, acc[rf][cf], 0, 0, 0);
      }
    }
    __syncthreads();  // drains stage + protects WAR on LDS buffers
  }

#pragma unroll
  for (int rf = 0; rf < 4; ++rf) {
    int rbase = bm + wr0 + rf * 16 + (lane >> 4) * 4;
#pragma unroll
    for (int cf = 0; cf < 4; ++cf) {
      int col = wc0 + cf * 16 + (lane & 15);
#pragma unroll
      for (int r = 0; r < 4; ++r) {
        int row = rbase + r;
        if (row < Nrows) {
          float v = acc[rf][cf][r];
          if (EPI) { v += bias[col]; v = fmaxf(v, 0.f); }
          C[(size_t)row * ldc + col] = pack_split(v);
        }
      }
    }
  }
}

// ---------------- aggregate v2: wave-per-node, 8B gathers, shfl bcast -------
// mean over neighbors of cols 0..127 of feat (PK: packed u32 / fp32).
// COMBINE=1: out = pack(relu(mean + unpack(radd) + bias)); else out = pack(mean).
template<int COMBINE, int PK>
__global__ __launch_bounds__(256) void aggregate2(
    const void* __restrict__ featv, int ldf,
    const int* __restrict__ rowptr, const int* __restrict__ ssrc,
    const u32* __restrict__ radd, int ldr, const float* __restrict__ bias,
    u32* __restrict__ out, int ldo, int n)
{
  const int lane = threadIdx.x & 63;
  const int i = blockIdx.x * 4 + (threadIdx.x >> 6);
  if (i >= n) return;
  const int s = rowptr[i], e = rowptr[i + 1];

  float a0 = 0.f, a1 = 0.f, b0 = 0.f, b1 = 0.f;
  float c0 = 0.f, c1 = 0.f, d0 = 0.f, d1 = 0.f;

  for (int base = s; base < e; base += 64) {
    int c = e - base; if (c > 64) c = 64;
    int idx = (lane < c) ? ssrc[base + lane] : 0;
    int t = 0;
    for (; t + 4 <= c; t += 4) {
      int j0 = __shfl(idx, t);
      int j1 = __shfl(idx, t + 1);
      int j2 = __shfl(idx, t + 2);
      int j3 = __shfl(idx, t + 3);
      if (PK) {
        uint2 p0 = *(const uint2*)((const u32*)featv + (size_t)j0 * ldf + 2 * lane);
        uint2 p1 = *(const uint2*)((const u32*)featv + (size_t)j1 * ldf + 2 * lane);
        uint2 p2 = *(const uint2*)((const u32*)featv + (size_t)j2 * ldf + 2 * lane);
        uint2 p3 = *(const uint2*)((const u32*)featv + (size_t)j3 * ldf + 2 * lane);
        a0 += unpack_val(p0.x); a1 += unpack_val(p0.y);
        b0 += unpack_val(p1.x); b1 += unpack_val(p1.y);
        c0 += unpack_val(p2.x); c1 += unpack_val(p2.y);
        d0 += unpack_val(p3.x); d1 += unpack_val(p3.y);
      } else {
        float2 p0 = *(const float2*)((const float*)featv + (size_t)j0 * ldf + 2 * lane);
        float2 p1 = *(const float2*)((const float*)featv + (size_t)j1 * ldf + 2 * lane);
        float2 p2 = *(const float2*)((const float*)featv + (size_t)j2 * ldf + 2 * lane);
        float2 p3 = *(const float2*)((const float*)featv + (size_t)j3 * ldf + 2 * lane);
        a0 += p0.x; a1 += p0.y;
        b0 += p1.x; b1 += p1.y;
        c0 += p2.x; c1 += p2.y;
        d0 += p3.x; d1 += p3.y;
      }
    }
    for (; t < c; ++t) {
      int j = __shfl(idx, t);
      if (PK) {
        uint2 p = *(const uint2*)((const u32*)featv + (size_t)j * ldf + 2 * lane);
        a0 += unpack_val(p.x); a1 += unpack_val(p.y);
      } else {
        float2 p = *(const float2*)((const float*)featv + (size_t)j * ldf + 2 * lane);
        a0 += p.x; a1 += p.y;
      }
    }
  }
  int d = e - s;
  float inv = 1.0f / (float)(d > 0 ? d : 1);
  float m0 = (a0 + b0 + c0 + d0) * inv;
  float m1 = (a1 + b1 + c1 + d1) * inv;
  if (COMBINE) {
    m0 = fmaxf(m0 + unpack_val(radd[(size_t)i * ldr + 2 * lane]) + bias[2 * lane], 0.f);
    m1 = fmaxf(m1 + unpack_val(radd[(size_t)i * ldr + 2 * lane + 1]) + bias[2 * lane + 1], 0.f);
  }
  uint2 o = make_uint2(pack_split(m0), pack_split(m1));
  *(uint2*)(out + (size_t)i * ldo + 2 * lane) = o;
}

// ---------------- final-layer reductions ----------------
__global__ __launch_bounds__(128) void reduce_uv_kernel(const u32* __restrict__ hp, int ldh,
                                                        const float* __restrict__ wsrc,
                                                        float* __restrict__ uv, int n) {
  int f = threadIdx.x;
  float u = 0.f, v = 0.f;
  for (int i = blockIdx.x; i < n; i += gridDim.x) {
    float hv = unpack_val(hp[(size_t)i * ldh + f]);
    u += wsrc[i] * hv;
    v += hv;
  }
  atomicAdd(&uv[f], u);
  atomicAdd(&uv[128 + f], v);
}

__global__ void final_kernel(const float* __restrict__ uv,
                             const float* __restrict__ w4l, const float* __restrict__ w4r,
                             const float* __restrict__ b4, float* __restrict__ out, int n) {
  __shared__ float p[10];
  int j = threadIdx.x;
  if (j < 10) {
    float s = 0.f;
    for (int k = 0; k < 128; ++k)
      s += uv[k] * w4l[k * 10 + j] + uv[128 + k] * w4r[k * 10 + j];
    float pooled = s * (1.0f / (float)n) + b4[j];
    p[j] = pooled;
    out[j] = pooled;
  }
  __syncthreads();
  if (j == 0) {
    float m = -1e30f;
    for (int t = 0; t < 10; ++t) m = fmaxf(m, p[t]);
    float sum = 0.f;
    for (int t = 0; t < 10; ++t) sum += expf(p[t] - m);
    float lse = m + logf(sum);
    for (int t = 0; t < 10; ++t) out[10 + t] = p[t] - lse;
  }
}

extern "C" void kernel_launch(void* const* d_in, const int* in_sizes, int n_in,
                              void* d_out, int out_size, void* d_ws, size_t ws_size,
                              hipStream_t stream) {
  const float* x   = (const float*)d_in[0];
  const int*   ei  = (const int*)d_in[1];     // int32 (JAX x64 disabled)
  const float* w1l = (const float*)d_in[2];
  const float* w1r = (const float*)d_in[3];
  const float* b1  = (const float*)d_in[4];
  const float* w2l = (const float*)d_in[5];
  const float* w2r = (const float*)d_in[6];
  const float* b2  = (const float*)d_in[7];
  const float* w3l = (const float*)d_in[8];
  const float* w3r = (const float*)d_in[9];
  const float* b3  = (const float*)d_in[10];
  const float* w4l = (const float*)d_in[11];
  const float* w4r = (const float*)d_in[12];
  const float* b4  = (const float*)d_in[13];

  const int N = in_sizes[0] / 128;   // 50000
  const int E = in_sizes[1] / 2;     // 800000
  const int* src = ei;
  const int* dst = ei + E;

  // workspace carve-up (256B aligned); ~107 MB (<= R6-proven budget)
  size_t off = 0;
  auto take = [&](size_t bytes) -> void* {
    void* p = (char*)d_ws + off;
    off += (bytes + 255) & ~(size_t)255;
    return p;
  };
  int*   deg    = (int*)take((size_t)N * 4);
  int*   rowptr = (int*)take((size_t)(N + 1) * 4);
  int*   offcur = (int*)take((size_t)N * 4);
  int*   ssrc   = (int*)take((size_t)E * 4);
  float* wsrc   = (float*)take((size_t)N * 4);
  int*   bsums  = (int*)take(256 * 4);
  float* uv     = (float*)take(256 * 4);
  u32*   P1     = (u32*)take(8 * 16 * 2048);   // [w1l ; w1r] K=256, M=256
  u32*   P2     = (u32*)take(8 * 16 * 2048);   // [w2l | w2r] K=256, M=256
  u32*   P3     = (u32*)take(8 * 8 * 2048);    // [w3r ; w3l] K=256, M=128
  u32*   bufA   = (u32*)take((size_t)N * 256 * 4);
  u32*   bufB   = (u32*)take((size_t)N * 256 * 4);
  (void)ws_size; (void)n_in; (void)out_size;

  const int EB = (E + 255) / 256;
  const int NB = (N + 255) / 256;
  const int GX = (N + TM - 1) / TM;     // 391
  const int GA = (N + 3) / 4;           // 12500 (aggregate2: 4 nodes/block)

  hipMemsetAsync(deg,  0, (size_t)N * 4, stream);
  hipMemsetAsync(wsrc, 0, (size_t)N * 4, stream);
  hipMemsetAsync(uv,   0, 256 * 4, stream);

  // ---- CSR build ----
  hist_kernel<<<EB, 256, 0, stream>>>(dst, deg, E, N);
  scan1_kernel<<<NB, 256, 0, stream>>>(deg, rowptr, bsums, N);
  scan2_kernel<<<1, 256, 0, stream>>>(bsums, NB);
  scan3_kernel<<<NB, 256, 0, stream>>>(rowptr, offcur, bsums, N, E);
  fill_kernel<<<EB, 256, 0, stream>>>(src, dst, offcur, ssrc, E, N);
  ws_kernel<<<EB, 256, 0, stream>>>(src, dst, deg, wsrc, E, N);

  // ---- conversions ----
  xconv_kernel<<<(N * 128 + 255) / 256, 256, 0, stream>>>(x, bufA, N * 128);
  wconv_kernel<<<16, 256, 0, stream>>>(w1l, 128, 256, P1, 256, 0);                 // ks 0..3
  wconv_kernel<<<16, 256, 0, stream>>>(w1r, 128, 256, P1 + 4 * 16 * 512, 256, 0);  // ks 4..7
  wconv_kernel<<<16, 256, 0, stream>>>(w2l, 256, 128, P2, 256, 0);
  wconv_kernel<<<16, 256, 0, stream>>>(w2r, 256, 128, P2, 256, 128);
  wconv_kernel<<<8, 256, 0, stream>>>(w3r, 128, 128, P3, 128, 0);                  // ks 0..3 (self)
  wconv_kernel<<<8, 256, 0, stream>>>(w3l, 128, 128, P3 + 4 * 8 * 512, 128, 0);    // ks 4..7 (agg)

  // ---- layer 1: bufA = [agg(x) | x]; bufB = relu(bufA @ [w1l;w1r] + b1) ----
  aggregate2<0, 0><<<GA, 256, 0, stream>>>(x, 128, rowptr, ssrc,
                                           nullptr, 0, nullptr, bufA, 256, N);
  mfma_gemm<1><<<dim3(GX, 2), 256, 0, stream>>>(bufA, 256, 8, P1, 16, b1, bufB, 256, N);

  // ---- layer 2 (gemm-first; h1 is 256-wide): bufA = h1 @ [w2l|w2r];
  //      h2 = relu(agg(y) + r + b2) -> bufB cols 0..127 ----
  mfma_gemm<0><<<dim3(GX, 2), 256, 0, stream>>>(bufB, 256, 8, P2, 16, nullptr, bufA, 256, N);
  aggregate2<1, 1><<<GA, 256, 0, stream>>>(bufA, 256, rowptr, ssrc,
                                           bufA + 128, 256, b2, bufB, 256, N);

  // ---- layers 3-5 (shared w3, aggregate-first):
  //      buf[.,128:256] = agg(buf[.,0:128]);  other = relu(buf @ [w3r;w3l] + b3)
  u32* cura = bufB;
  u32* curb = bufA;
  for (int rep = 0; rep < 3; ++rep) {
    aggregate2<0, 1><<<GA, 256, 0, stream>>>(cura, 256, rowptr, ssrc,
                                             nullptr, 0, nullptr, cura + 128, 256, N);
    mfma_gemm<1><<<dim3(GX, 1), 256, 0, stream>>>(cura, 256, 8, P3, 8, b3, curb, 256, N);
    u32* tmp = cura; cura = curb; curb = tmp;
  }

  // ---- layer 6 + global mean pool, collapsed (h5 in cura cols 0..127) ----
  reduce_uv_kernel<<<256, 128, 0, stream>>>(cura, 256, wsrc, uv, N);
  final_kernel<<<1, 64, 0, stream>>>(uv, w4l, w4r, b4, (float*)d_out, N);
}

// Round 10
// 627.560 us; speedup vs baseline: 1.5211x; 1.1997x over previous
//
#include <hip/hip_runtime.h>
#include <hip/hip_bf16.h>
#include <cstdint>

// GraphSAGE fused pipeline for MI355X — R10.
// R9 (753 µs): aggregate2 is HBM-fetch-bound (188 MB/dispatch @3.7 TB/s random
// gather; VALUBusy 30%). Lever: BYTES. R10:
//  (1) bf16 gather tables [N,128] (256 B/row, half of packed u32): producers
//      (xconv / GEMM epilogue / L2 combine) also emit a bf16 copy. GEMM
//      A-self and weight paths stay split-bf16 3-product (near-fp32) — the
//      only new error is per-node-independent table rounding, which cancels
//      in the deg-mean and the N=50k global pool. Predict absmax <= 5e-4.
//  (2) in-place GEMM (each block reads only its own rows; epilogue after all
//      staged reads drain) -> single packed buffer P [N,256] + two tables.
//  (3) fused wconv (6->1) and fill+ws (2->1) dispatches.

typedef unsigned int u32;
typedef unsigned short u16;
typedef __bf16 bf16x8 __attribute__((ext_vector_type(8)));
typedef float f32x4 __attribute__((ext_vector_type(4)));

typedef __attribute__((address_space(1))) const u32 gu32;
typedef __attribute__((address_space(3))) u32 lu32;

__device__ __forceinline__ u32 bf16_hi_bits(float x) {
  u32 u = __float_as_uint(x);
  return (u + 0x7fffu + ((u >> 16) & 1u)) & 0xffff0000u;  // RNE bf16 in high 16
}
__device__ __forceinline__ u32 pack_split(float v) {
  u32 hb = bf16_hi_bits(v);
  float lo = v - __uint_as_float(hb);
  return hb | (bf16_hi_bits(lo) >> 16);
}
__device__ __forceinline__ float unpack_val(u32 p) {
  return __uint_as_float(p & 0xffff0000u) + __uint_as_float(p << 16);
}
__device__ __forceinline__ int clampi(int v, int n) {
  return v < 0 ? 0 : (v >= n ? n - 1 : v);
}

// ---------------- CSR build ----------------
__global__ void hist_kernel(const int* __restrict__ dst, int* __restrict__ deg, int e, int n) {
  int i = blockIdx.x * 256 + threadIdx.x;
  if (i < e) atomicAdd(&deg[clampi(dst[i], n)], 1);
}
__global__ void scan1_kernel(const int* __restrict__ deg, int* __restrict__ part,
                             int* __restrict__ bsums, int n) {
  __shared__ int s[256];
  int t = threadIdx.x;
  int i = blockIdx.x * 256 + t;
  int v = (i < n) ? deg[i] : 0;
  s[t] = v;
  __syncthreads();
  for (int o = 1; o < 256; o <<= 1) {
    int add = (t >= o) ? s[t - o] : 0;
    __syncthreads();
    s[t] += add;
    __syncthreads();
  }
  if (i < n) part[i] = s[t] - v;
  if (t == 255) bsums[blockIdx.x] = s[255];
}
__global__ void scan2_kernel(int* __restrict__ bsums, int nb) {
  __shared__ int s[256];
  int t = threadIdx.x;
  int v = (t < nb) ? bsums[t] : 0;
  s[t] = v;
  __syncthreads();
  for (int o = 1; o < 256; o <<= 1) {
    int add = (t >= o) ? s[t - o] : 0;
    __syncthreads();
    s[t] += add;
    __syncthreads();
  }
  if (t < nb) bsums[t] = s[t] - v;
}
__global__ void scan3_kernel(int* __restrict__ rowptr, int* __restrict__ offcur,
                             const int* __restrict__ bsums, int n, int total) {
  int i = blockIdx.x * 256 + threadIdx.x;
  if (i < n) {
    int v = rowptr[i] + bsums[blockIdx.x];
    rowptr[i] = v;
    offcur[i] = v;
  }
  if (i == 0) rowptr[n] = total;
}
// fill CSR adjacency + final-layer src weights in one pass (deg final after hist)
__global__ void fill_ws_kernel(const int* __restrict__ src, const int* __restrict__ dst,
                               const int* __restrict__ deg, int* __restrict__ offcur,
                               int* __restrict__ ssrc, float* __restrict__ wsrc, int e, int n) {
  int i = blockIdx.x * 256 + threadIdx.x;
  if (i < e) {
    int di = clampi(dst[i], n);
    int si = clampi(src[i], n);
    int p = atomicAdd(&offcur[di], 1);
    ssrc[p] = si;
    int d = deg[di];
    atomicAdd(&wsrc[si], 1.0f / (float)(d > 0 ? d : 1));
  }
}

// ---------------- conversions ----------------
// x [N,128] fp32 -> packed u32 into P cols 128..255 AND bf16 into table T
__global__ void xconv_kernel(const float* __restrict__ x, u32* __restrict__ P,
                             u16* __restrict__ T, int n) {
  int i = blockIdx.x * 256 + threadIdx.x;
  if (i < n) {
    float v = x[i];
    P[(size_t)(i >> 7) * 256 + 128 + (i & 127)] = pack_split(v);
    T[i] = (u16)(bf16_hi_bits(v) >> 16);
  }
}

// all 6 weight planes in one launch (blocks 0..79)
__global__ void wconv_all(const float* __restrict__ w1l, const float* __restrict__ w1r,
                          const float* __restrict__ w2l, const float* __restrict__ w2r,
                          const float* __restrict__ w3l, const float* __restrict__ w3r,
                          u32* __restrict__ P1, u32* __restrict__ P2, u32* __restrict__ P3) {
  int b = blockIdx.x;
  const float* src; int K, Msrc, Mtot, colbase, lb; u32* plane;
  if      (b < 16) { src = w1l; K = 128; Msrc = 256; plane = P1;                Mtot = 256; colbase = 0;   lb = b; }
  else if (b < 32) { src = w1r; K = 128; Msrc = 256; plane = P1 + 4 * 16 * 512; Mtot = 256; colbase = 0;   lb = b - 16; }
  else if (b < 48) { src = w2l; K = 256; Msrc = 128; plane = P2;                Mtot = 256; colbase = 0;   lb = b - 32; }
  else if (b < 64) { src = w2r; K = 256; Msrc = 128; plane = P2;                Mtot = 256; colbase = 128; lb = b - 48; }
  else if (b < 72) { src = w3r; K = 128; Msrc = 128; plane = P3;                Mtot = 128; colbase = 0;   lb = b - 64; }
  else             { src = w3l; K = 128; Msrc = 128; plane = P3 + 4 * 8 * 512;  Mtot = 128; colbase = 0;   lb = b - 72; }
  int t = lb * 256 + threadIdx.x;
  int lane = t & 63, fi = t >> 6;
  int nfc = Msrc >> 4;
  if (fi >= (K >> 5) * nfc) return;
  int ks = fi / nfc, cfl = fi - ks * nfc;
  int col = cfl * 16 + (lane & 15);
  int kb = ks * 32 + (lane >> 4) * 8;
  u32 hw[4], lw[4];
#pragma unroll
  for (int jj = 0; jj < 4; ++jj) {
    u32 p0 = pack_split(src[(size_t)(kb + 2 * jj) * Msrc + col]);
    u32 p1 = pack_split(src[(size_t)(kb + 2 * jj + 1) * Msrc + col]);
    hw[jj] = (p0 >> 16) | (p1 & 0xffff0000u);
    lw[jj] = (p0 & 0xffffu) | (p1 << 16);
  }
  u32* d = plane + ((size_t)(ks * (Mtot >> 4) + (colbase >> 4) + cfl) * 64 + lane) * 8;
  *(uint4*)d = make_uint4(hw[0], hw[1], hw[2], hw[3]);
  *(uint4*)(d + 4) = make_uint4(lw[0], lw[1], lw[2], lw[3]);
}

// ---------------- MFMA GEMM (split-bf16 3-product, in-place safe) ----------
// TBL=0: packed C only. TBL=1: col<128 -> bf16 table ONLY, col>=128 -> packed.
// TBL=2: packed C AND bf16 table (cols<128; M=128 case).
#define TM 128

template<int EPI, int TBL>
__global__ __launch_bounds__(256) void mfma_gemm(
    const u32* __restrict__ A, int lda, int nk,
    const u32* __restrict__ F, int mcols,
    const float* __restrict__ bias,
    u32* __restrict__ C, int ldc, u16* __restrict__ tbl, int Nrows)
{
  __shared__ u32 lds[2][4096];
  const int tid = threadIdx.x;
  const int lane = tid & 63;
  const int wid = tid >> 6;
  const int bm = blockIdx.x * TM;
  const int wr0 = (wid >> 1) * 64;
  const int wc0 = blockIdx.y * 128 + (wid & 1) * 64;

  f32x4 acc[4][4] = {};

  auto stage = [&](int kk, int buf) {
#pragma unroll
    for (int iss = 0; iss < 4; ++iss) {
      int s = iss * 256 + tid;
      int row = s >> 3, slot = s & 7;
      int g = slot ^ (row & 7);
      int grow = bm + row;
      if (grow >= Nrows) grow = Nrows - 1;
      const u32* gp = A + (size_t)grow * lda + kk * 32 + g * 4;
      u32* lp = &lds[buf][(size_t)(iss * 256 + (tid & ~63)) * 4];
      __builtin_amdgcn_global_load_lds((gu32*)gp, (lu32*)lp, 16, 0, 0);
    }
  };

  stage(0, 0);
  __syncthreads();

  for (int t = 0; t < nk; ++t) {
    const int cur = t & 1;
    uint4 bh[4], bl[4];
#pragma unroll
    for (int cf = 0; cf < 4; ++cf) {
      const u32* fb = F + ((size_t)(t * mcols + (wc0 >> 4) + cf) * 64 + lane) * 8;
      bh[cf] = *(const uint4*)fb;
      bl[cf] = *(const uint4*)(fb + 4);
    }
    if (t + 1 < nk) stage(t + 1, cur ^ 1);

    bf16x8 ah[4], al[4];
#pragma unroll
    for (int rf = 0; rf < 4; ++rf) {
      int row = wr0 + rf * 16 + (lane & 15);
      int g0 = (lane >> 4) * 2;
      const uint4 c0 = *(const uint4*)&lds[cur][(size_t)(row * 8 + (g0 ^ (row & 7))) * 4];
      const uint4 c1 = *(const uint4*)&lds[cur][(size_t)(row * 8 + ((g0 + 1) ^ (row & 7))) * 4];
      u32 u[8] = {c0.x, c0.y, c0.z, c0.w, c1.x, c1.y, c1.z, c1.w};
      union { u32 w[4]; bf16x8 v; } H, L;
#pragma unroll
      for (int j = 0; j < 4; ++j) {
        H.w[j] = (u[2 * j] >> 16) | (u[2 * j + 1] & 0xffff0000u);
        L.w[j] = (u[2 * j] & 0xffffu) | (u[2 * j + 1] << 16);
      }
      ah[rf] = H.v;
      al[rf] = L.v;
    }
#pragma unroll
    for (int rf = 0; rf < 4; ++rf) {
#pragma unroll
      for (int cf = 0; cf < 4; ++cf) {
        union { uint4 q; bf16x8 v; } BH, BL;
        BH.q = bh[cf];
        BL.q = bl[cf];
        acc[rf][cf] = __builtin_amdgcn_mfma_f32_16x16x32_bf16(ah[rf], BH.v, acc[rf][cf], 0, 0, 0);
        acc[rf][cf] = __builtin_amdgcn_mfma_f32_16x16x32_bf16(al[rf], BH.v, acc[rf][cf], 0, 0, 0);
        acc[rf][cf] = __builtin_amdgcn_mfma_f32_16x16x32_bf16(ah[rf], BL.v, acc[rf][cf], 0, 0, 0);
      }
    }
    __syncthreads();
  }

#pragma unroll
  for (int rf = 0; rf < 4; ++rf) {
    int rbase = bm + wr0 + rf * 16 + (lane >> 4) * 4;
#pragma unroll
    for (int cf = 0; cf < 4; ++cf) {
      int col = wc0 + cf * 16 + (lane & 15);
#pragma unroll
      for (int r = 0; r < 4; ++r) {
        int row = rbase + r;
        if (row < Nrows) {
          float v = acc[rf][cf][r];
          if (EPI) { v += bias[col]; v = fmaxf(v, 0.f); }
          if (TBL == 0) {
            C[(size_t)row * ldc + col] = pack_split(v);
          } else if (TBL == 1) {
            if (col < 128) tbl[(size_t)row * 128 + col] = (u16)(bf16_hi_bits(v) >> 16);
            else           C[(size_t)row * ldc + col] = pack_split(v);
          } else {
            C[(size_t)row * ldc + col] = pack_split(v);
            tbl[(size_t)row * 128 + col] = (u16)(bf16_hi_bits(v) >> 16);
          }
        }
      }
    }
  }
}

// ---------------- aggregate v3: wave-per-node, bf16 table gather -----------
// gt: [n,128] bf16 (256 B/row; lane reads u32 = 2 cols). mean over neighbors.
// COMBINE=1: += unpack(radd) + bias, relu; write packed + bf16 table copy.
template<int COMBINE>
__global__ __launch_bounds__(256) void aggregate3(
    const u16* __restrict__ gt,
    const int* __restrict__ rowptr, const int* __restrict__ ssrc,
    const u32* __restrict__ radd, const float* __restrict__ bias,
    u32* __restrict__ outp, u16* __restrict__ outt, int n)
{
  const int lane = threadIdx.x & 63;
  const int i = blockIdx.x * 4 + (threadIdx.x >> 6);
  if (i >= n) return;
  const int s = rowptr[i], e = rowptr[i + 1];

  float a0 = 0.f, a1 = 0.f, b0 = 0.f, b1 = 0.f;
  float c0 = 0.f, c1 = 0.f, d0 = 0.f, d1 = 0.f;

  for (int base = s; base < e; base += 64) {
    int c = e - base; if (c > 64) c = 64;
    int idx = (lane < c) ? ssrc[base + lane] : 0;
    int t = 0;
    for (; t + 4 <= c; t += 4) {
      int j0 = __shfl(idx, t);
      int j1 = __shfl(idx, t + 1);
      int j2 = __shfl(idx, t + 2);
      int j3 = __shfl(idx, t + 3);
      u32 p0 = *(const u32*)(gt + (size_t)j0 * 128 + 2 * lane);
      u32 p1 = *(const u32*)(gt + (size_t)j1 * 128 + 2 * lane);
      u32 p2 = *(const u32*)(gt + (size_t)j2 * 128 + 2 * lane);
      u32 p3 = *(const u32*)(gt + (size_t)j3 * 128 + 2 * lane);
      a0 += __uint_as_float(p0 << 16); a1 += __uint_as_float(p0 & 0xffff0000u);
      b0 += __uint_as_float(p1 << 16); b1 += __uint_as_float(p1 & 0xffff0000u);
      c0 += __uint_as_float(p2 << 16); c1 += __uint_as_float(p2 & 0xffff0000u);
      d0 += __uint_as_float(p3 << 16); d1 += __uint_as_float(p3 & 0xffff0000u);
    }
    for (; t < c; ++t) {
      int j = __shfl(idx, t);
      u32 p = *(const u32*)(gt + (size_t)j * 128 + 2 * lane);
      a0 += __uint_as_float(p << 16); a1 += __uint_as_float(p & 0xffff0000u);
    }
  }
  int d = e - s;
  float inv = 1.0f / (float)(d > 0 ? d : 1);
  float m0 = (a0 + b0 + c0 + d0) * inv;
  float m1 = (a1 + b1 + c1 + d1) * inv;
  if (COMBINE) {
    m0 = fmaxf(m0 + unpack_val(radd[(size_t)i * 256 + 2 * lane]) + bias[2 * lane], 0.f);
    m1 = fmaxf(m1 + unpack_val(radd[(size_t)i * 256 + 2 * lane + 1]) + bias[2 * lane + 1], 0.f);
  }
  *(uint2*)(outp + (size_t)i * 256 + 2 * lane) = make_uint2(pack_split(m0), pack_split(m1));
  if (COMBINE)
    *(u32*)(outt + (size_t)i * 128 + 2 * lane) = (bf16_hi_bits(m0) >> 16) | bf16_hi_bits(m1);
}

// ---------------- final-layer reductions ----------------
__global__ __launch_bounds__(128) void reduce_uv_kernel(const u32* __restrict__ hp, int ldh,
                                                        const float* __restrict__ wsrc,
                                                        float* __restrict__ uv, int n) {
  int f = threadIdx.x;
  float u = 0.f, v = 0.f;
  for (int i = blockIdx.x; i < n; i += gridDim.x) {
    float hv = unpack_val(hp[(size_t)i * ldh + f]);
    u += wsrc[i] * hv;
    v += hv;
  }
  atomicAdd(&uv[f], u);
  atomicAdd(&uv[128 + f], v);
}

__global__ void final_kernel(const float* __restrict__ uv,
                             const float* __restrict__ w4l, const float* __restrict__ w4r,
                             const float* __restrict__ b4, float* __restrict__ out, int n) {
  __shared__ float p[10];
  int j = threadIdx.x;
  if (j < 10) {
    float s = 0.f;
    for (int k = 0; k < 128; ++k)
      s += uv[k] * w4l[k * 10 + j] + uv[128 + k] * w4r[k * 10 + j];
    float pooled = s * (1.0f / (float)n) + b4[j];
    p[j] = pooled;
    out[j] = pooled;
  }
  __syncthreads();
  if (j == 0) {
    float m = -1e30f;
    for (int t = 0; t < 10; ++t) m = fmaxf(m, p[t]);
    float sum = 0.f;
    for (int t = 0; t < 10; ++t) sum += expf(p[t] - m);
    float lse = m + logf(sum);
    for (int t = 0; t < 10; ++t) out[10 + t] = p[t] - lse;
  }
}

extern "C" void kernel_launch(void* const* d_in, const int* in_sizes, int n_in,
                              void* d_out, int out_size, void* d_ws, size_t ws_size,
                              hipStream_t stream) {
  const float* x   = (const float*)d_in[0];
  const int*   ei  = (const int*)d_in[1];     // int32 (JAX x64 disabled)
  const float* w1l = (const float*)d_in[2];
  const float* w1r = (const float*)d_in[3];
  const float* b1  = (const float*)d_in[4];
  const float* w2l = (const float*)d_in[5];
  const float* w2r = (const float*)d_in[6];
  const float* b2  = (const float*)d_in[7];
  const float* w3l = (const float*)d_in[8];
  const float* w3r = (const float*)d_in[9];
  const float* b3  = (const float*)d_in[10];
  const float* w4l = (const float*)d_in[11];
  const float* w4r = (const float*)d_in[12];
  const float* b4  = (const float*)d_in[13];

  const int N = in_sizes[0] / 128;   // 50000
  const int E = in_sizes[1] / 2;     // 800000
  const int* src = ei;
  const int* dst = ei + E;

  // workspace (256B aligned); ~82 MB (well under R9-proven ~107 MB)
  size_t off = 0;
  auto take = [&](size_t bytes) -> void* {
    void* p = (char*)d_ws + off;
    off += (bytes + 255) & ~(size_t)255;
    return p;
  };
  int*   deg    = (int*)take((size_t)N * 4);
  int*   rowptr = (int*)take((size_t)(N + 1) * 4);
  int*   offcur = (int*)take((size_t)N * 4);
  int*   ssrc   = (int*)take((size_t)E * 4);
  float* wsrc   = (float*)take((size_t)N * 4);
  int*   bsums  = (int*)take(256 * 4);
  float* uv     = (float*)take(256 * 4);
  u32*   P1     = (u32*)take(8 * 16 * 2048);   // [w1l ; w1r] K=256, M=256
  u32*   P2     = (u32*)take(8 * 16 * 2048);   // [w2l | w2r] K=256, M=256
  u32*   P3     = (u32*)take(8 * 8 * 2048);    // [w3r ; w3l] K=256, M=128
  u32*   P      = (u32*)take((size_t)N * 256 * 4);  // packed activations, in-place
  u16*   T0     = (u16*)take((size_t)N * 128 * 2);  // bf16 gather tables
  u16*   T1     = (u16*)take((size_t)N * 128 * 2);
  (void)ws_size; (void)n_in; (void)out_size;

  const int EB = (E + 255) / 256;
  const int NB = (N + 255) / 256;
  const int GX = (N + TM - 1) / TM;     // 391
  const int GA = (N + 3) / 4;           // 12500

  hipMemsetAsync(deg,  0, (size_t)N * 4, stream);
  hipMemsetAsync(wsrc, 0, (size_t)N * 4, stream);
  hipMemsetAsync(uv,   0, 256 * 4, stream);

  // ---- CSR build ----
  hist_kernel<<<EB, 256, 0, stream>>>(dst, deg, E, N);
  scan1_kernel<<<NB, 256, 0, stream>>>(deg, rowptr, bsums, N);
  scan2_kernel<<<1, 256, 0, stream>>>(bsums, NB);
  scan3_kernel<<<NB, 256, 0, stream>>>(rowptr, offcur, bsums, N, E);
  fill_ws_kernel<<<EB, 256, 0, stream>>>(src, dst, deg, offcur, ssrc, wsrc, E, N);

  // ---- conversions ----
  xconv_kernel<<<(N * 128 + 255) / 256, 256, 0, stream>>>(x, P, T0, N * 128);
  wconv_all<<<80, 256, 0, stream>>>(w1l, w1r, w2l, w2r, w3l, w3r, P1, P2, P3);

  // ---- layer 1: P = [agg(x)|x] -> h1 (in-place, all 256 cols) ----
  aggregate3<0><<<GA, 256, 0, stream>>>(T0, rowptr, ssrc, nullptr, nullptr, P, nullptr, N);
  mfma_gemm<1, 0><<<dim3(GX, 2), 256, 0, stream>>>(P, 256, 8, P1, 16, b1, P, 256, nullptr, N);

  // ---- layer 2: y -> T0 (bf16), r -> P cols 128-255; h2 -> P cols 0-127 + T1 ----
  mfma_gemm<0, 1><<<dim3(GX, 2), 256, 0, stream>>>(P, 256, 8, P2, 16, nullptr, P, 256, T0, N);
  aggregate3<1><<<GA, 256, 0, stream>>>(T0, rowptr, ssrc, P + 128, b2, P, T1, N);

  // ---- layers 3-5 (shared w3, aggregate-first, tables alternate) ----
  u16* tR = T1;
  u16* tW = T0;
  for (int rep = 0; rep < 3; ++rep) {
    aggregate3<0><<<GA, 256, 0, stream>>>(tR, rowptr, ssrc, nullptr, nullptr, P + 128, nullptr, N);
    mfma_gemm<1, 2><<<dim3(GX, 1), 256, 0, stream>>>(P, 256, 8, P3, 8, b3, P, 256, tW, N);
    u16* tmp = tR; tR = tW; tW = tmp;
  }

  // ---- layer 6 + global mean pool, collapsed (h5 in P cols 0-127) ----
  reduce_uv_kernel<<<256, 128, 0, stream>>>(P, 256, wsrc, uv, N);
  final_kernel<<<1, 64, 0, stream>>>(uv, w4l, w4r, b4, (float*)d_out, N);
}

// Round 13
// 599.727 us; speedup vs baseline: 1.5917x; 1.0464x over previous
//
#include <hip/hip_runtime.h>
#include <hip/hip_bf16.h>
#include <cstdint>

// GraphSAGE fused pipeline for MI355X — R11 (resubmit ×2; never ran: broker).
// R10 (627.6 µs): fill_ws is #1 at 78.6 µs — 1.6M device-scope atomics bypass
// per-XCD L2 (WRITE_SIZE 81 MB for 3.4 MB of logical output, VALUBusy 0.8%).
// R11: rank-returning histogram. hist's atomicAdd(&deg[dst],1) RETURN VALUE is
// the edge's rank in its bucket -> store er[e]; fill then places ssrc with a
// plain scattered write (rowptr[dst]+er[e]) — offcur pass (800k return-atomics)
// deleted. Only wsrc's 800k float atomics remain (grouping-by-src would cost
// the same atomics elsewhere). Everything else byte-identical to R10-green.

typedef unsigned int u32;
typedef unsigned short u16;
typedef __bf16 bf16x8 __attribute__((ext_vector_type(8)));
typedef float f32x4 __attribute__((ext_vector_type(4)));

typedef __attribute__((address_space(1))) const u32 gu32;
typedef __attribute__((address_space(3))) u32 lu32;

__device__ __forceinline__ u32 bf16_hi_bits(float x) {
  u32 u = __float_as_uint(x);
  return (u + 0x7fffu + ((u >> 16) & 1u)) & 0xffff0000u;  // RNE bf16 in high 16
}
__device__ __forceinline__ u32 pack_split(float v) {
  u32 hb = bf16_hi_bits(v);
  float lo = v - __uint_as_float(hb);
  return hb | (bf16_hi_bits(lo) >> 16);
}
__device__ __forceinline__ float unpack_val(u32 p) {
  return __uint_as_float(p & 0xffff0000u) + __uint_as_float(p << 16);
}
__device__ __forceinline__ int clampi(int v, int n) {
  return v < 0 ? 0 : (v >= n ? n - 1 : v);
}

// ---------------- CSR build ----------------
// histogram + per-edge rank (the atomic's return value IS the rank)
__global__ void hist_rank_kernel(const int* __restrict__ dst, int* __restrict__ deg,
                                 int* __restrict__ er, int e, int n) {
  int i = blockIdx.x * 256 + threadIdx.x;
  if (i < e) er[i] = atomicAdd(&deg[clampi(dst[i], n)], 1);
}
__global__ void scan1_kernel(const int* __restrict__ deg, int* __restrict__ part,
                             int* __restrict__ bsums, int n) {
  __shared__ int s[256];
  int t = threadIdx.x;
  int i = blockIdx.x * 256 + t;
  int v = (i < n) ? deg[i] : 0;
  s[t] = v;
  __syncthreads();
  for (int o = 1; o < 256; o <<= 1) {
    int add = (t >= o) ? s[t - o] : 0;
    __syncthreads();
    s[t] += add;
    __syncthreads();
  }
  if (i < n) part[i] = s[t] - v;
  if (t == 255) bsums[blockIdx.x] = s[255];
}
__global__ void scan2_kernel(int* __restrict__ bsums, int nb) {
  __shared__ int s[256];
  int t = threadIdx.x;
  int v = (t < nb) ? bsums[t] : 0;
  s[t] = v;
  __syncthreads();
  for (int o = 1; o < 256; o <<= 1) {
    int add = (t >= o) ? s[t - o] : 0;
    __syncthreads();
    s[t] += add;
    __syncthreads();
  }
  if (t < nb) bsums[t] = s[t] - v;
}
__global__ void scan3_kernel(int* __restrict__ rowptr, const int* __restrict__ bsums,
                             int n, int total) {
  int i = blockIdx.x * 256 + threadIdx.x;
  if (i < n) rowptr[i] += bsums[blockIdx.x];
  if (i == 0) rowptr[n] = total;
}
// place edges (no placement atomics: slot = rowptr[dst] + er[e]) + wsrc atomics
__global__ void fill_ws_kernel(const int* __restrict__ src, const int* __restrict__ dst,
                               const int* __restrict__ er, const int* __restrict__ rowptr,
                               int* __restrict__ ssrc, float* __restrict__ wsrc, int e, int n) {
  int i = blockIdx.x * 256 + threadIdx.x;
  if (i < e) {
    int di = clampi(dst[i], n);
    int si = clampi(src[i], n);
    int r0 = rowptr[di];
    int d = rowptr[di + 1] - r0;
    ssrc[r0 + er[i]] = si;
    atomicAdd(&wsrc[si], 1.0f / (float)(d > 0 ? d : 1));
  }
}

// ---------------- conversions ----------------
// x [N,128] fp32 -> packed u32 into P cols 128..255 AND bf16 into table T
__global__ void xconv_kernel(const float* __restrict__ x, u32* __restrict__ P,
                             u16* __restrict__ T, int n) {
  int i = blockIdx.x * 256 + threadIdx.x;
  if (i < n) {
    float v = x[i];
    P[(size_t)(i >> 7) * 256 + 128 + (i & 127)] = pack_split(v);
    T[i] = (u16)(bf16_hi_bits(v) >> 16);
  }
}

// all 6 weight planes in one launch (blocks 0..79)
__global__ void wconv_all(const float* __restrict__ w1l, const float* __restrict__ w1r,
                          const float* __restrict__ w2l, const float* __restrict__ w2r,
                          const float* __restrict__ w3l, const float* __restrict__ w3r,
                          u32* __restrict__ P1, u32* __restrict__ P2, u32* __restrict__ P3) {
  int b = blockIdx.x;
  const float* src; int K, Msrc, Mtot, colbase, lb; u32* plane;
  if      (b < 16) { src = w1l; K = 128; Msrc = 256; plane = P1;                Mtot = 256; colbase = 0;   lb = b; }
  else if (b < 32) { src = w1r; K = 128; Msrc = 256; plane = P1 + 4 * 16 * 512; Mtot = 256; colbase = 0;   lb = b - 16; }
  else if (b < 48) { src = w2l; K = 256; Msrc = 128; plane = P2;                Mtot = 256; colbase = 0;   lb = b - 32; }
  else if (b < 64) { src = w2r; K = 256; Msrc = 128; plane = P2;                Mtot = 256; colbase = 128; lb = b - 48; }
  else if (b < 72) { src = w3r; K = 128; Msrc = 128; plane = P3;                Mtot = 128; colbase = 0;   lb = b - 64; }
  else             { src = w3l; K = 128; Msrc = 128; plane = P3 + 4 * 8 * 512;  Mtot = 128; colbase = 0;   lb = b - 72; }
  int t = lb * 256 + threadIdx.x;
  int lane = t & 63, fi = t >> 6;
  int nfc = Msrc >> 4;
  if (fi >= (K >> 5) * nfc) return;
  int ks = fi / nfc, cfl = fi - ks * nfc;
  int col = cfl * 16 + (lane & 15);
  int kb = ks * 32 + (lane >> 4) * 8;
  u32 hw[4], lw[4];
#pragma unroll
  for (int jj = 0; jj < 4; ++jj) {
    u32 p0 = pack_split(src[(size_t)(kb + 2 * jj) * Msrc + col]);
    u32 p1 = pack_split(src[(size_t)(kb + 2 * jj + 1) * Msrc + col]);
    hw[jj] = (p0 >> 16) | (p1 & 0xffff0000u);
    lw[jj] = (p0 & 0xffffu) | (p1 << 16);
  }
  u32* d = plane + ((size_t)(ks * (Mtot >> 4) + (colbase >> 4) + cfl) * 64 + lane) * 8;
  *(uint4*)d = make_uint4(hw[0], hw[1], hw[2], hw[3]);
  *(uint4*)(d + 4) = make_uint4(lw[0], lw[1], lw[2], lw[3]);
}

// ---------------- MFMA GEMM (split-bf16 3-product, in-place safe) ----------
// TBL=0: packed C only. TBL=1: col<128 -> bf16 table ONLY, col>=128 -> packed.
// TBL=2: packed C AND bf16 table (cols<128; M=128 case).
#define TM 128

template<int EPI, int TBL>
__global__ __launch_bounds__(256) void mfma_gemm(
    const u32* __restrict__ A, int lda, int nk,
    const u32* __restrict__ F, int mcols,
    const float* __restrict__ bias,
    u32* __restrict__ C, int ldc, u16* __restrict__ tbl, int Nrows)
{
  __shared__ u32 lds[2][4096];
  const int tid = threadIdx.x;
  const int lane = tid & 63;
  const int wid = tid >> 6;
  const int bm = blockIdx.x * TM;
  const int wr0 = (wid >> 1) * 64;
  const int wc0 = blockIdx.y * 128 + (wid & 1) * 64;

  f32x4 acc[4][4] = {};

  auto stage = [&](int kk, int buf) {
#pragma unroll
    for (int iss = 0; iss < 4; ++iss) {
      int s = iss * 256 + tid;
      int row = s >> 3, slot = s & 7;
      int g = slot ^ (row & 7);
      int grow = bm + row;
      if (grow >= Nrows) grow = Nrows - 1;
      const u32* gp = A + (size_t)grow * lda + kk * 32 + g * 4;
      u32* lp = &lds[buf][(size_t)(iss * 256 + (tid & ~63)) * 4];
      __builtin_amdgcn_global_load_lds((gu32*)gp, (lu32*)lp, 16, 0, 0);
    }
  };

  stage(0, 0);
  __syncthreads();

  for (int t = 0; t < nk; ++t) {
    const int cur = t & 1;
    uint4 bh[4], bl[4];
#pragma unroll
    for (int cf = 0; cf < 4; ++cf) {
      const u32* fb = F + ((size_t)(t * mcols + (wc0 >> 4) + cf) * 64 + lane) * 8;
      bh[cf] = *(const uint4*)fb;
      bl[cf] = *(const uint4*)(fb + 4);
    }
    if (t + 1 < nk) stage(t + 1, cur ^ 1);

    bf16x8 ah[4], al[4];
#pragma unroll
    for (int rf = 0; rf < 4; ++rf) {
      int row = wr0 + rf * 16 + (lane & 15);
      int g0 = (lane >> 4) * 2;
      const uint4 c0 = *(const uint4*)&lds[cur][(size_t)(row * 8 + (g0 ^ (row & 7))) * 4];
      const uint4 c1 = *(const uint4*)&lds[cur][(size_t)(row * 8 + ((g0 + 1) ^ (row & 7))) * 4];
      u32 u[8] = {c0.x, c0.y, c0.z, c0.w, c1.x, c1.y, c1.z, c1.w};
      union { u32 w[4]; bf16x8 v; } H, L;
#pragma unroll
      for (int j = 0; j < 4; ++j) {
        H.w[j] = (u[2 * j] >> 16) | (u[2 * j + 1] & 0xffff0000u);
        L.w[j] = (u[2 * j] & 0xffffu) | (u[2 * j + 1] << 16);
      }
      ah[rf] = H.v;
      al[rf] = L.v;
    }
#pragma unroll
    for (int rf = 0; rf < 4; ++rf) {
#pragma unroll
      for (int cf = 0; cf < 4; ++cf) {
        union { uint4 q; bf16x8 v; } BH, BL;
        BH.q = bh[cf];
        BL.q = bl[cf];
        acc[rf][cf] = __builtin_amdgcn_mfma_f32_16x16x32_bf16(ah[rf], BH.v, acc[rf][cf], 0, 0, 0);
        acc[rf][cf] = __builtin_amdgcn_mfma_f32_16x16x32_bf16(al[rf], BH.v, acc[rf][cf], 0, 0, 0);
        acc[rf][cf] = __builtin_amdgcn_mfma_f32_16x16x32_bf16(ah[rf], BL.v, acc[rf][cf], 0, 0, 0);
      }
    }
    __syncthreads();
  }

#pragma unroll
  for (int rf = 0; rf < 4; ++rf) {
    int rbase = bm + wr0 + rf * 16 + (lane >> 4) * 4;
#pragma unroll
    for (int cf = 0; cf < 4; ++cf) {
      int col = wc0 + cf * 16 + (lane & 15);
#pragma unroll
      for (int r = 0; r < 4; ++r) {
        int row = rbase + r;
        if (row < Nrows) {
          float v = acc[rf][cf][r];
          if (EPI) { v += bias[col]; v = fmaxf(v, 0.f); }
          if (TBL == 0) {
            C[(size_t)row * ldc + col] = pack_split(v);
          } else if (TBL == 1) {
            if (col < 128) tbl[(size_t)row * 128 + col] = (u16)(bf16_hi_bits(v) >> 16);
            else           C[(size_t)row * ldc + col] = pack_split(v);
          } else {
            C[(size_t)row * ldc + col] = pack_split(v);
            tbl[(size_t)row * 128 + col] = (u16)(bf16_hi_bits(v) >> 16);
          }
        }
      }
    }
  }
}

// ---------------- aggregate v3: wave-per-node, bf16 table gather -----------
template<int COMBINE>
__global__ __launch_bounds__(256) void aggregate3(
    const u16* __restrict__ gt,
    const int* __restrict__ rowptr, const int* __restrict__ ssrc,
    const u32* __restrict__ radd, const float* __restrict__ bias,
    u32* __restrict__ outp, u16* __restrict__ outt, int n)
{
  const int lane = threadIdx.x & 63;
  const int i = blockIdx.x * 4 + (threadIdx.x >> 6);
  if (i >= n) return;
  const int s = rowptr[i], e = rowptr[i + 1];

  float a0 = 0.f, a1 = 0.f, b0 = 0.f, b1 = 0.f;
  float c0 = 0.f, c1 = 0.f, d0 = 0.f, d1 = 0.f;

  for (int base = s; base < e; base += 64) {
    int c = e - base; if (c > 64) c = 64;
    int idx = (lane < c) ? ssrc[base + lane] : 0;
    int t = 0;
    for (; t + 4 <= c; t += 4) {
      int j0 = __shfl(idx, t);
      int j1 = __shfl(idx, t + 1);
      int j2 = __shfl(idx, t + 2);
      int j3 = __shfl(idx, t + 3);
      u32 p0 = *(const u32*)(gt + (size_t)j0 * 128 + 2 * lane);
      u32 p1 = *(const u32*)(gt + (size_t)j1 * 128 + 2 * lane);
      u32 p2 = *(const u32*)(gt + (size_t)j2 * 128 + 2 * lane);
      u32 p3 = *(const u32*)(gt + (size_t)j3 * 128 + 2 * lane);
      a0 += __uint_as_float(p0 << 16); a1 += __uint_as_float(p0 & 0xffff0000u);
      b0 += __uint_as_float(p1 << 16); b1 += __uint_as_float(p1 & 0xffff0000u);
      c0 += __uint_as_float(p2 << 16); c1 += __uint_as_float(p2 & 0xffff0000u);
      d0 += __uint_as_float(p3 << 16); d1 += __uint_as_float(p3 & 0xffff0000u);
    }
    for (; t < c; ++t) {
      int j = __shfl(idx, t);
      u32 p = *(const u32*)(gt + (size_t)j * 128 + 2 * lane);
      a0 += __uint_as_float(p << 16); a1 += __uint_as_float(p & 0xffff0000u);
    }
  }
  int d = e - s;
  float inv = 1.0f / (float)(d > 0 ? d : 1);
  float m0 = (a0 + b0 + c0 + d0) * inv;
  float m1 = (a1 + b1 + c1 + d1) * inv;
  if (COMBINE) {
    m0 = fmaxf(m0 + unpack_val(radd[(size_t)i * 256 + 2 * lane]) + bias[2 * lane], 0.f);
    m1 = fmaxf(m1 + unpack_val(radd[(size_t)i * 256 + 2 * lane + 1]) + bias[2 * lane + 1], 0.f);
  }
  *(uint2*)(outp + (size_t)i * 256 + 2 * lane) = make_uint2(pack_split(m0), pack_split(m1));
  if (COMBINE)
    *(u32*)(outt + (size_t)i * 128 + 2 * lane) = (bf16_hi_bits(m0) >> 16) | bf16_hi_bits(m1);
}

// ---------------- final-layer reductions ----------------
__global__ __launch_bounds__(128) void reduce_uv_kernel(const u32* __restrict__ hp, int ldh,
                                                        const float* __restrict__ wsrc,
                                                        float* __restrict__ uv, int n) {
  int f = threadIdx.x;
  float u = 0.f, v = 0.f;
  for (int i = blockIdx.x; i < n; i += gridDim.x) {
    float hv = unpack_val(hp[(size_t)i * ldh + f]);
    u += wsrc[i] * hv;
    v += hv;
  }
  atomicAdd(&uv[f], u);
  atomicAdd(&uv[128 + f], v);
}

__global__ void final_kernel(const float* __restrict__ uv,
                             const float* __restrict__ w4l, const float* __restrict__ w4r,
                             const float* __restrict__ b4, float* __restrict__ out, int n) {
  __shared__ float p[10];
  int j = threadIdx.x;
  if (j < 10) {
    float s = 0.f;
    for (int k = 0; k < 128; ++k)
      s += uv[k] * w4l[k * 10 + j] + uv[128 + k] * w4r[k * 10 + j];
    float pooled = s * (1.0f / (float)n) + b4[j];
    p[j] = pooled;
    out[j] = pooled;
  }
  __syncthreads();
  if (j == 0) {
    float m = -1e30f;
    for (int t = 0; t < 10; ++t) m = fmaxf(m, p[t]);
    float sum = 0.f;
    for (int t = 0; t < 10; ++t) sum += expf(p[t] - m);
    float lse = m + logf(sum);
    for (int t = 0; t < 10; ++t) out[10 + t] = p[t] - lse;
  }
}

extern "C" void kernel_launch(void* const* d_in, const int* in_sizes, int n_in,
                              void* d_out, int out_size, void* d_ws, size_t ws_size,
                              hipStream_t stream) {
  const float* x   = (const float*)d_in[0];
  const int*   ei  = (const int*)d_in[1];     // int32 (JAX x64 disabled)
  const float* w1l = (const float*)d_in[2];
  const float* w1r = (const float*)d_in[3];
  const float* b1  = (const float*)d_in[4];
  const float* w2l = (const float*)d_in[5];
  const float* w2r = (const float*)d_in[6];
  const float* b2  = (const float*)d_in[7];
  const float* w3l = (const float*)d_in[8];
  const float* w3r = (const float*)d_in[9];
  const float* b3  = (const float*)d_in[10];
  const float* w4l = (const float*)d_in[11];
  const float* w4r = (const float*)d_in[12];
  const float* b4  = (const float*)d_in[13];

  const int N = in_sizes[0] / 128;   // 50000
  const int E = in_sizes[1] / 2;     // 800000
  const int* src = ei;
  const int* dst = ei + E;

  // workspace (256B aligned); ~85 MB
  size_t off = 0;
  auto take = [&](size_t bytes) -> void* {
    void* p = (char*)d_ws + off;
    off += (bytes + 255) & ~(size_t)255;
    return p;
  };
  int*   deg    = (int*)take((size_t)N * 4);
  int*   rowptr = (int*)take((size_t)(N + 1) * 4);
  int*   er     = (int*)take((size_t)E * 4);       // per-edge rank in dst bucket
  int*   ssrc   = (int*)take((size_t)E * 4);
  float* wsrc   = (float*)take((size_t)N * 4);
  int*   bsums  = (int*)take(256 * 4);
  float* uv     = (float*)take(256 * 4);
  u32*   P1     = (u32*)take(8 * 16 * 2048);   // [w1l ; w1r] K=256, M=256
  u32*   P2     = (u32*)take(8 * 16 * 2048);   // [w2l | w2r] K=256, M=256
  u32*   P3     = (u32*)take(8 * 8 * 2048);    // [w3r ; w3l] K=256, M=128
  u32*   P      = (u32*)take((size_t)N * 256 * 4);  // packed activations, in-place
  u16*   T0     = (u16*)take((size_t)N * 128 * 2);  // bf16 gather tables
  u16*   T1     = (u16*)take((size_t)N * 128 * 2);
  (void)ws_size; (void)n_in; (void)out_size;

  const int EB = (E + 255) / 256;
  const int NB = (N + 255) / 256;
  const int GX = (N + TM - 1) / TM;     // 391
  const int GA = (N + 3) / 4;           // 12500

  hipMemsetAsync(deg,  0, (size_t)N * 4, stream);
  hipMemsetAsync(wsrc, 0, (size_t)N * 4, stream);
  hipMemsetAsync(uv,   0, 256 * 4, stream);

  // ---- CSR build (rank-atomic scheme) ----
  hist_rank_kernel<<<EB, 256, 0, stream>>>(dst, deg, er, E, N);
  scan1_kernel<<<NB, 256, 0, stream>>>(deg, rowptr, bsums, N);
  scan2_kernel<<<1, 256, 0, stream>>>(bsums, NB);
  scan3_kernel<<<NB, 256, 0, stream>>>(rowptr, bsums, N, E);
  fill_ws_kernel<<<EB, 256, 0, stream>>>(src, dst, er, rowptr, ssrc, wsrc, E, N);

  // ---- conversions ----
  xconv_kernel<<<(N * 128 + 255) / 256, 256, 0, stream>>>(x, P, T0, N * 128);
  wconv_all<<<80, 256, 0, stream>>>(w1l, w1r, w2l, w2r, w3l, w3r, P1, P2, P3);

  // ---- layer 1: P = [agg(x)|x] -> h1 (in-place, all 256 cols) ----
  aggregate3<0><<<GA, 256, 0, stream>>>(T0, rowptr, ssrc, nullptr, nullptr, P, nullptr, N);
  mfma_gemm<1, 0><<<dim3(GX, 2), 256, 0, stream>>>(P, 256, 8, P1, 16, b1, P, 256, nullptr, N);

  // ---- layer 2: y -> T0 (bf16), r -> P cols 128-255; h2 -> P cols 0-127 + T1 ----
  mfma_gemm<0, 1><<<dim3(GX, 2), 256, 0, stream>>>(P, 256, 8, P2, 16, nullptr, P, 256, T0, N);
  aggregate3<1><<<GA, 256, 0, stream>>>(T0, rowptr, ssrc, P + 128, b2, P, T1, N);

  // ---- layers 3-5 (shared w3, aggregate-first, tables alternate) ----
  u16* tR = T1;
  u16* tW = T0;
  for (int rep = 0; rep < 3; ++rep) {
    aggregate3<0><<<GA, 256, 0, stream>>>(tR, rowptr, ssrc, nullptr, nullptr, P + 128, nullptr, N);
    mfma_gemm<1, 2><<<dim3(GX, 1), 256, 0, stream>>>(P, 256, 8, P3, 8, b3, P, 256, tW, N);
    u16* tmp = tR; tR = tW; tW = tmp;
  }

  // ---- layer 6 + global mean pool, collapsed (h5 in P cols 0-127) ----
  reduce_uv_kernel<<<256, 128, 0, stream>>>(P, 256, wsrc, uv, N);
  final_kernel<<<1, 64, 0, stream>>>(uv, w4l, w4r, b4, (float*)d_out, N);
}